// Round 4
// baseline (537.324 us; speedup 1.0000x reference)
//
#include <hip/hip_runtime.h>

// NeRF renderer pipeline for MI355X (gfx950).
// R4: register-resident weights. R3 showed k_density latency-bound with no
// saturated pipe and occupancy-insensitive -> the 32 L2 weight loads inside
// every K-loop were the serialized latency. Now each wave preloads its
// 64-feature weight slice ONCE (128 VGPRs) and each WG streams 4 point-tiles
// through it; K-loop = ds_read_b128 + MFMA only. Density L1 is MFMA'd (K=3
// padded to 32); color gather vectorized via remapped X layout.

typedef float f32x4 __attribute__((ext_vector_type(4)));
typedef __bf16 bf16x8 __attribute__((ext_vector_type(8)));
typedef unsigned short u16x8 __attribute__((ext_vector_type(8)));
typedef unsigned short u16x4 __attribute__((ext_vector_type(4)));

#define NRAYS 2048
#define NSTEP 128
#define TSAMP 256
#define MIN_NEAR 0.05f
#define DTPW 4   // density tiles (64 pts) per workgroup
#define CTPW 4   // color tiles per workgroup

__device__ __forceinline__ unsigned short f2bf(float f) {
  unsigned int u = __float_as_uint(f);
  u += 0x7FFFu + ((u >> 16) & 1u);   // round-to-nearest-even
  return (unsigned short)(u >> 16);
}

// ---------------------------------------------------------------- weight pack
// dst[((kt*NT+nt)*64+lane)*8+j] = W[k][n], k=kt*32+(lane>>4)*8+j, n=nt*16+(lane&15)
// A-operand frag of the swapped layer: A[m=n][k] = W[k][n].
__global__ void k_pack(const float* __restrict__ W, unsigned short* __restrict__ dst,
                       int K, int Norig, int NT, int total) {
  int idx = blockIdx.x * 256 + threadIdx.x;
  if (idx >= total) return;
  int per = NT * 512;
  int kt = idx / per;
  int rm = idx % per;
  int nt = rm >> 9;
  int lane = (rm >> 3) & 63;
  int j = rm & 7;
  int k = kt * 32 + ((lane >> 4) << 3) + j;
  int n = nt * 16 + (lane & 15);
  float v = (k < K && n < Norig) ? W[k * Norig + n] : 0.0f;
  dst[idx] = f2bf(v);
}

// Color L1 pack with remapped input layout:
// X[c]: c0..15 = out16 row (sigma ignored, weight 0), c16..18 = dir, rest 0.
// k==0 -> 0; 1<=k<16 -> cW1 row 2+k (geo); 16<=k<19 -> cW1 row k-16 (dir).
__global__ void k_pack_c1(const float* __restrict__ cW1, unsigned short* __restrict__ dst) {
  int idx = blockIdx.x * 256 + threadIdx.x;  // total 8192
  int nt = idx >> 9;
  int lane = (idx >> 3) & 63;
  int j = idx & 7;
  int k = ((lane >> 4) << 3) + j;   // 0..31
  int n = nt * 16 + (lane & 15);
  float v = 0.0f;
  if (k >= 1 && k < 16) v = cW1[(2 + k) * 256 + n];
  else if (k >= 16 && k < 19) v = cW1[(k - 16) * 256 + n];
  dst[idx] = f2bf(v);
}

// ---------------------------------------------------------------- ray setup
__global__ void k_raysetup(const float* __restrict__ o, const float* __restrict__ d,
                           float* __restrict__ z_c) {
  int r = blockIdx.x, i = threadIdx.x;  // 128 threads
  float ox = o[r * 3], oy = o[r * 3 + 1], oz = o[r * 3 + 2];
  float dx = d[r * 3], dy = d[r * 3 + 1], dz = d[r * 3 + 2];
  float b = ox * dx + oy * dy + oz * dz;
  float c = ox * ox + oy * oy + oz * oz - 1.0f;
  float disc = fmaxf(b * b - c, 0.0f);
  float zmax = fmaxf(-b + sqrtf(disc), MIN_NEAR + 1e-3f);
  float zmin = MIN_NEAR;
  float t = (float)i / 127.0f;
  float z = zmin + (zmax - zmin) * t;
  z = fminf(fmaxf(z, zmin), zmax);
  z_c[r * NSTEP + i] = z;
}

// ---------------------------------------------------------------- density MLP
// LDS act layout: h[p][n] at u16 offset p*256 + ((n>>3)^(p&31))*8 + (n&7)
// xb layout: X[p][c] at u16 offset p*32 + ((g^(p&3))*8) + (c&7), g=c>>3
__global__ __launch_bounds__(256, 2)
void k_density(const float* __restrict__ rays_o, const float* __restrict__ rays_d,
               const float* __restrict__ z,
               const unsigned short* __restrict__ Wp1, const float* __restrict__ b1,
               const unsigned short* __restrict__ Wp2, const float* __restrict__ b2,
               const unsigned short* __restrict__ Wp3, const float* __restrict__ b3,
               float* __restrict__ out16) {
  __shared__ unsigned short buf[64 * 256];
  __shared__ unsigned short xb[64 * 32];
  const int t = threadIdx.x;
  const int lane = t & 63;
  const int wid = t >> 6;
  const int quad = lane >> 4;
  const int col = lane & 15;

  // ---- one-time register-resident weight preload (wave's 64-feature slice)
  bf16x8 w1r[4], w2r[8][4];
#pragma unroll
  for (int ntl = 0; ntl < 4; ++ntl)
    w1r[ntl] = *reinterpret_cast<const bf16x8*>(Wp1 + ((wid * 4 + ntl) * 64 + lane) * 8);
#pragma unroll
  for (int kt = 0; kt < 8; ++kt)
#pragma unroll
    for (int ntl = 0; ntl < 4; ++ntl)
      w2r[kt][ntl] = *reinterpret_cast<const bf16x8*>(Wp2 + ((kt * 16 + wid * 4 + ntl) * 64 + lane) * 8);

  for (int tt = 0; tt < DTPW; ++tt) {
    const int P0 = (blockIdx.x * DTPW + tt) * 64;
    { // build X = [x,y,z,0..] bf16 rows (4 threads/point, one u16x8 each)
      int p = t >> 2, g = t & 3;
      int P = P0 + p, r = P >> 7;
      u16x8 pk = {0, 0, 0, 0, 0, 0, 0, 0};
      if (g == 0) {
        float zz = z[P];
        pk[0] = f2bf(rays_o[r * 3 + 0] + rays_d[r * 3 + 0] * zz);
        pk[1] = f2bf(rays_o[r * 3 + 1] + rays_d[r * 3 + 1] * zz);
        pk[2] = f2bf(rays_o[r * 3 + 2] + rays_d[r * 3 + 2] * zz);
      }
      *reinterpret_cast<u16x8*>(&xb[p * 32 + ((g ^ (p & 3)) * 8)]) = pk;
    }
    __syncthreads();  // B1: xb ready; prev tile's buf reads retired
    { // L1: K=32 MFMA, h1 -> buf
      f32x4 acc[16];
#pragma unroll
      for (int i = 0; i < 16; ++i) acc[i] = (f32x4){0.f, 0.f, 0.f, 0.f};
      bf16x8 x[4];
#pragma unroll
      for (int pt = 0; pt < 4; ++pt) {
        int p = pt * 16 + col;
        x[pt] = *reinterpret_cast<const bf16x8*>(&xb[p * 32 + ((quad ^ (p & 3)) * 8)]);
      }
#pragma unroll
      for (int ntl = 0; ntl < 4; ++ntl)
#pragma unroll
        for (int pt = 0; pt < 4; ++pt)
          acc[ntl * 4 + pt] = __builtin_amdgcn_mfma_f32_16x16x32_bf16(w1r[ntl], x[pt], acc[ntl * 4 + pt], 0, 0, 0);
#pragma unroll
      for (int ntl = 0; ntl < 4; ++ntl) {
        int n = (wid * 4 + ntl) * 16 + quad * 4;
        f32x4 bv = *reinterpret_cast<const f32x4*>(b1 + n);
#pragma unroll
        for (int pt = 0; pt < 4; ++pt) {
          int p = pt * 16 + col;
          u16x4 pk;
#pragma unroll
          for (int rr = 0; rr < 4; ++rr)
            pk[rr] = f2bf(fmaxf(acc[ntl * 4 + pt][rr] + bv[rr], 0.0f));
          *reinterpret_cast<u16x4*>(&buf[p * 256 + (((n >> 3) ^ (p & 31)) * 8) + (n & 7)]) = pk;
        }
      }
    }
    __syncthreads();  // B2: h1 complete
    { // L2: 256x256, weights in registers, x streamed from LDS
      f32x4 acc[16];
#pragma unroll
      for (int i = 0; i < 16; ++i) acc[i] = (f32x4){0.f, 0.f, 0.f, 0.f};
#pragma unroll
      for (int kt = 0; kt < 8; ++kt) {
        bf16x8 x[4];
#pragma unroll
        for (int pt = 0; pt < 4; ++pt) {
          int p = pt * 16 + col;
          x[pt] = *reinterpret_cast<const bf16x8*>(&buf[p * 256 + (((kt * 4 + quad) ^ (p & 31)) * 8)]);
        }
#pragma unroll
        for (int ntl = 0; ntl < 4; ++ntl)
#pragma unroll
          for (int pt = 0; pt < 4; ++pt)
            acc[ntl * 4 + pt] = __builtin_amdgcn_mfma_f32_16x16x32_bf16(w2r[kt][ntl], x[pt], acc[ntl * 4 + pt], 0, 0, 0);
      }
      __syncthreads();  // B3: all buf reads done before in-place overwrite
#pragma unroll
      for (int ntl = 0; ntl < 4; ++ntl) {
        int n = (wid * 4 + ntl) * 16 + quad * 4;
        f32x4 bv = *reinterpret_cast<const f32x4*>(b2 + n);
#pragma unroll
        for (int pt = 0; pt < 4; ++pt) {
          int p = pt * 16 + col;
          u16x4 pk;
#pragma unroll
          for (int rr = 0; rr < 4; ++rr)
            pk[rr] = f2bf(fmaxf(acc[ntl * 4 + pt][rr] + bv[rr], 0.0f));
          *reinterpret_cast<u16x4*>(&buf[p * 256 + (((n >> 3) ^ (p & 31)) * 8) + (n & 7)]) = pk;
        }
      }
    }
    __syncthreads();  // B4: h2 complete
    { // L3: 256 -> 16 (sigma + geo); wave wid owns p-tile wid
      const int p = wid * 16 + col;
      f32x4 acc = {0.f, 0.f, 0.f, 0.f};
#pragma unroll
      for (int kt = 0; kt < 8; ++kt) {
        bf16x8 w = *reinterpret_cast<const bf16x8*>(&Wp3[(kt * 64 + lane) * 8]);
        bf16x8 x = *reinterpret_cast<const bf16x8*>(&buf[p * 256 + (((kt * 4 + quad) ^ (p & 31)) * 8)]);
        acc = __builtin_amdgcn_mfma_f32_16x16x32_bf16(w, x, acc, 0, 0, 0);
      }
      int n0 = quad * 4;
      f32x4 bv = *reinterpret_cast<const f32x4*>(b3 + n0);
      f32x4 v;
#pragma unroll
      for (int rr = 0; rr < 4; ++rr) v[rr] = acc[rr] + bv[rr];
      if (quad == 0) v[0] = expf(fminf(fmaxf(v[0], -15.f), 15.f));  // trunc_exp
      *reinterpret_cast<f32x4*>(out16 + (size_t)(P0 + p) * 16 + n0) = v;
    }
    // next tile's B1 separates this tile's L3 buf-reads from the next writes
  }
}

// ------------------------------------------------- coarse weights + sample_pdf
__global__ void k_pdf(const float* __restrict__ z_c, const float* __restrict__ out16_c,
                      float* __restrict__ z_f) {
  __shared__ float sz[128], sl[128], sw[128], scdf[128], szmid[128];
  int r = blockIdx.x, i = threadIdx.x;  // 128 threads
  float zi = z_c[r * NSTEP + i];
  sz[i] = zi;
  float sg = out16_c[(size_t)(r * NSTEP + i) * 16];
  __syncthreads();
  float aug = (i < 127) ? (sz[i + 1] - zi) : (sz[127] - sz[126]);
  float alpha = 1.0f - expf(-aug * sg);
  float term = 1.0f - alpha + 1e-15f;
  sl[i] = logf(term);
  __syncthreads();
  for (int off = 1; off < 128; off <<= 1) {  // inclusive scan of log-terms
    float y = (i >= off) ? sl[i - off] : 0.0f;
    __syncthreads();
    sl[i] += y;
    __syncthreads();
  }
  float excl = (i > 0) ? sl[i - 1] : 0.0f;
  float w = alpha * expf(excl);
  sw[i] = w;
  __syncthreads();
  float v = (i < 126) ? (sw[i + 1] + 1e-5f) : 0.0f;  // weights[:,1:-1] + 1e-5
  sl[i] = v;
  __syncthreads();
  for (int off = 1; off < 128; off <<= 1) {
    float y = (i >= off) ? sl[i - off] : 0.0f;
    __syncthreads();
    sl[i] += y;
    __syncthreads();
  }
  float total = sl[125];
  if (i <= 126) scdf[i] = (i == 0) ? 0.0f : sl[i - 1] / total;
  if (i < 127) szmid[i] = 0.5f * (sz[i] + sz[i + 1]);
  __syncthreads();
  const float lo = 0.5f / 128.0f, hi = 1.0f - 0.5f / 128.0f;
  float u = lo + (hi - lo) * ((float)i / 127.0f);
  int loI = 0, hiI = 127;  // searchsorted right over scdf[0..126]
  while (loI < hiI) {
    int mid = (loI + hiI) >> 1;
    if (scdf[mid] > u) hiI = mid; else loI = mid + 1;
  }
  int inds = loI;
  int below = inds - 1; if (below < 0) below = 0; if (below > 126) below = 126;
  int above = inds; if (above > 126) above = 126;
  float c0 = scdf[below], c1 = scdf[above];
  float b0 = szmid[below], b1 = szmid[above];
  float dn = c1 - c0; if (dn < 1e-5f) dn = 1.0f;
  float tt = (u - c0) / dn;
  z_f[r * NSTEP + i] = b0 + tt * (b1 - b0);
}

// ---------------------------------------------- merge (stable) + final weights
__global__ void k_merge(const float* __restrict__ z_c, const float* __restrict__ z_f,
                        const float* __restrict__ out16_c, const float* __restrict__ out16_f,
                        float* __restrict__ z_m, int* __restrict__ order,
                        float* __restrict__ wgt) {
  __shared__ float szc[128], szf[128], szm[256], sl[256];
  __shared__ int sord[256];
  int r = blockIdx.x, t = threadIdx.x;  // 256 threads
  if (t < 128) szc[t] = z_c[r * NSTEP + t];
  else szf[t - 128] = z_f[r * NSTEP + t - 128];
  __syncthreads();
  int pos; float myz;
  if (t < 128) {  // coarse i: pos = i + #{zf < zc[i]}   (ties: coarse first)
    myz = szc[t];
    int lo = 0, hi = 128;
    while (lo < hi) { int m = (lo + hi) >> 1; if (szf[m] < myz) lo = m + 1; else hi = m; }
    pos = t + lo;
  } else {        // fine j: pos = j + #{zc <= zf[j]}
    int j = t - 128; myz = szf[j];
    int lo = 0, hi = 128;
    while (lo < hi) { int m = (lo + hi) >> 1; if (szc[m] <= myz) lo = m + 1; else hi = m; }
    pos = j + lo;
  }
  szm[pos] = myz; sord[pos] = t;
  __syncthreads();
  z_m[r * TSAMP + t] = szm[t];
  order[r * TSAMP + t] = sord[t];
  int src = sord[t];
  float sg = (src < 128) ? out16_c[(size_t)(r * NSTEP + src) * 16]
                         : out16_f[(size_t)(r * NSTEP + src - 128) * 16];
  float zt = szm[t];
  float aug = (t < 255) ? (szm[t + 1] - zt) : (szm[255] - szm[254]);
  float alpha = 1.0f - expf(-aug * sg);
  sl[t] = logf(1.0f - alpha + 1e-15f);
  __syncthreads();
  for (int off = 1; off < 256; off <<= 1) {
    float y = (t >= off) ? sl[t - off] : 0.0f;
    __syncthreads();
    sl[t] += y;
    __syncthreads();
  }
  float excl = (t > 0) ? sl[t - 1] : 0.0f;
  wgt[r * TSAMP + t] = alpha * expf(excl);
}

// ---------------------------------------------------------------- color MLP
__global__ __launch_bounds__(256, 2)
void k_color(const float* __restrict__ rays_d, const int* __restrict__ order,
             const float* __restrict__ wgt,
             const float* __restrict__ out16_c, const float* __restrict__ out16_f,
             const unsigned short* __restrict__ Wp1, const float* __restrict__ cb1,
             const unsigned short* __restrict__ Wp2, const float* __restrict__ cb2,
             const unsigned short* __restrict__ Wp3, const float* __restrict__ cb3,
             float* __restrict__ rgb4) {
  __shared__ unsigned short buf[64 * 256];
  __shared__ unsigned short xb[64 * 32];
  const int t = threadIdx.x;
  const int lane = t & 63;
  const int wid = t >> 6;
  const int quad = lane >> 4;
  const int col = lane & 15;

  bf16x8 w1r[4], w2r[8][4];
#pragma unroll
  for (int ntl = 0; ntl < 4; ++ntl)
    w1r[ntl] = *reinterpret_cast<const bf16x8*>(Wp1 + ((wid * 4 + ntl) * 64 + lane) * 8);
#pragma unroll
  for (int kt = 0; kt < 8; ++kt)
#pragma unroll
    for (int ntl = 0; ntl < 4; ++ntl)
      w2r[kt][ntl] = *reinterpret_cast<const bf16x8*>(Wp2 + ((kt * 16 + wid * 4 + ntl) * 64 + lane) * 8);

  for (int tt = 0; tt < CTPW; ++tt) {
    const int P0 = (blockIdx.x * CTPW + tt) * 64;
    int pred = 0;
    { // build X = [out16 row(16) | dir(3) | 0...] (4 threads/point, u16x8 each)
      int p = t >> 2, g = t & 3;
      int P = P0 + p, r = P >> 8;
      u16x8 pk = {0, 0, 0, 0, 0, 0, 0, 0};
      if (g < 2) {
        int src = order[P];
        const float* g16 = (src < 128) ? (out16_c + (size_t)(r * NSTEP + src) * 16)
                                       : (out16_f + (size_t)(r * NSTEP + src - 128) * 16);
        f32x4 a = *reinterpret_cast<const f32x4*>(g16 + g * 8);
        f32x4 b = *reinterpret_cast<const f32x4*>(g16 + g * 8 + 4);
#pragma unroll
        for (int i = 0; i < 4; ++i) { pk[i] = f2bf(a[i]); pk[4 + i] = f2bf(b[i]); }
      } else if (g == 2) {
        pk[0] = f2bf(rays_d[r * 3 + 0]);
        pk[1] = f2bf(rays_d[r * 3 + 1]);
        pk[2] = f2bf(rays_d[r * 3 + 2]);
      } else {
        pred = (wgt[P] > 1e-4f) ? 1 : 0;
      }
      *reinterpret_cast<u16x8*>(&xb[p * 32 + ((g ^ (p & 3)) * 8)]) = pk;
    }
    if (!__syncthreads_or(pred)) continue;  // whole tile masked: rgb never read
    { // L1: K=32 MFMA, h1 -> buf
      f32x4 acc[16];
#pragma unroll
      for (int i = 0; i < 16; ++i) acc[i] = (f32x4){0.f, 0.f, 0.f, 0.f};
      bf16x8 x[4];
#pragma unroll
      for (int pt = 0; pt < 4; ++pt) {
        int p = pt * 16 + col;
        x[pt] = *reinterpret_cast<const bf16x8*>(&xb[p * 32 + ((quad ^ (p & 3)) * 8)]);
      }
#pragma unroll
      for (int ntl = 0; ntl < 4; ++ntl)
#pragma unroll
        for (int pt = 0; pt < 4; ++pt)
          acc[ntl * 4 + pt] = __builtin_amdgcn_mfma_f32_16x16x32_bf16(w1r[ntl], x[pt], acc[ntl * 4 + pt], 0, 0, 0);
#pragma unroll
      for (int ntl = 0; ntl < 4; ++ntl) {
        int n = (wid * 4 + ntl) * 16 + quad * 4;
        f32x4 bv = *reinterpret_cast<const f32x4*>(cb1 + n);
#pragma unroll
        for (int pt = 0; pt < 4; ++pt) {
          int p = pt * 16 + col;
          u16x4 pk;
#pragma unroll
          for (int rr = 0; rr < 4; ++rr)
            pk[rr] = f2bf(fmaxf(acc[ntl * 4 + pt][rr] + bv[rr], 0.0f));
          *reinterpret_cast<u16x4*>(&buf[p * 256 + (((n >> 3) ^ (p & 31)) * 8) + (n & 7)]) = pk;
        }
      }
    }
    __syncthreads();  // B2
    { // L2: 256x256, register weights
      f32x4 acc[16];
#pragma unroll
      for (int i = 0; i < 16; ++i) acc[i] = (f32x4){0.f, 0.f, 0.f, 0.f};
#pragma unroll
      for (int kt = 0; kt < 8; ++kt) {
        bf16x8 x[4];
#pragma unroll
        for (int pt = 0; pt < 4; ++pt) {
          int p = pt * 16 + col;
          x[pt] = *reinterpret_cast<const bf16x8*>(&buf[p * 256 + (((kt * 4 + quad) ^ (p & 31)) * 8)]);
        }
#pragma unroll
        for (int ntl = 0; ntl < 4; ++ntl)
#pragma unroll
          for (int pt = 0; pt < 4; ++pt)
            acc[ntl * 4 + pt] = __builtin_amdgcn_mfma_f32_16x16x32_bf16(w2r[kt][ntl], x[pt], acc[ntl * 4 + pt], 0, 0, 0);
      }
      __syncthreads();  // B3
#pragma unroll
      for (int ntl = 0; ntl < 4; ++ntl) {
        int n = (wid * 4 + ntl) * 16 + quad * 4;
        f32x4 bv = *reinterpret_cast<const f32x4*>(cb2 + n);
#pragma unroll
        for (int pt = 0; pt < 4; ++pt) {
          int p = pt * 16 + col;
          u16x4 pk;
#pragma unroll
          for (int rr = 0; rr < 4; ++rr)
            pk[rr] = f2bf(fmaxf(acc[ntl * 4 + pt][rr] + bv[rr], 0.0f));
          *reinterpret_cast<u16x4*>(&buf[p * 256 + (((n >> 3) ^ (p & 31)) * 8) + (n & 7)]) = pk;
        }
      }
    }
    __syncthreads();  // B4
    { // L3: 256 -> 3 (padded 16), sigmoid; wave wid owns p-tile wid
      const int p = wid * 16 + col;
      f32x4 acc = {0.f, 0.f, 0.f, 0.f};
#pragma unroll
      for (int kt = 0; kt < 8; ++kt) {
        bf16x8 w = *reinterpret_cast<const bf16x8*>(&Wp3[(kt * 64 + lane) * 8]);
        bf16x8 x = *reinterpret_cast<const bf16x8*>(&buf[p * 256 + (((kt * 4 + quad) ^ (p & 31)) * 8)]);
        acc = __builtin_amdgcn_mfma_f32_16x16x32_bf16(w, x, acc, 0, 0, 0);
      }
      if (quad == 0) {
        f32x4 v;
#pragma unroll
        for (int rr = 0; rr < 3; ++rr) {
          float s = acc[rr] + cb3[rr];
          v[rr] = 1.0f / (1.0f + expf(-s));
        }
        v[3] = 0.0f;
        *reinterpret_cast<f32x4*>(rgb4 + (size_t)(P0 + p) * 4) = v;
      }
    }
  }
}

// ------------------------------------------------------- final per-ray outputs
__device__ __forceinline__ float block_reduce(float v, float* s, int t) {
  s[t] = v;
  __syncthreads();
  for (int off = 128; off > 0; off >>= 1) {
    if (t < off) s[t] += s[t + off];
    __syncthreads();
  }
  float r = s[0];
  __syncthreads();
  return r;
}

__global__ void k_final(const float* __restrict__ z_m, const float* __restrict__ wgt,
                        const float* __restrict__ rgb4, float* __restrict__ out) {
  __shared__ float sz[256], sw[256], smid[256], sred[256];
  int r = blockIdx.x, t = threadIdx.x;  // 256 threads
  float zt = z_m[r * TSAMP + t];
  float wt = wgt[r * TSAMP + t];
  sz[t] = zt; sw[t] = wt;
  __syncthreads();
  float znext = (t < 255) ? sz[t + 1] : (1.0f / 128.0f);  // sample_dist
  smid[t] = 0.5f * zt + 0.5f * znext;
  float cr = 0.f, cg = 0.f, cb = 0.f;
  if (wt > 1e-4f) {
    f32x4 c = *reinterpret_cast<const f32x4*>(rgb4 + (size_t)(r * TSAMP + t) * 4);
    cr = c[0]; cg = c[1]; cb = c[2];
  }
  __syncthreads();
  float mt = smid[t];
  float acc = 0.f;
  for (int j = 0; j < 256; ++j) acc += fabsf(mt - smid[j]) * sw[j];
  acc *= wt;
  float wsum = block_reduce(wt, sred, t);
  float depth = block_reduce(wt * zt, sred, t);
  float ir = block_reduce(wt * cr, sred, t);
  float ig = block_reduce(wt * cg, sred, t);
  float ib = block_reduce(wt * cb, sred, t);
  float S = block_reduce(acc, sred, t);
  if (t == 0) {
    const float bgc = 206.0f / 255.0f;
    float loss = S / (depth + 1e-6f);
    if (loss < 1e-3f) loss = 0.0f;
    out[r * 5 + 0] = ir + (1.0f - wsum) * bgc;
    out[r * 5 + 1] = ig + (1.0f - wsum) * bgc;
    out[r * 5 + 2] = ib + (1.0f - wsum) * bgc;
    out[r * 5 + 3] = depth;
    out[r * 5 + 4] = loss;
  }
}

// ---------------------------------------------------------------- launch
extern "C" void kernel_launch(void* const* d_in, const int* in_sizes, int n_in,
                              void* d_out, int out_size, void* d_ws, size_t ws_size,
                              hipStream_t stream) {
  const float* rays_o = (const float*)d_in[0];
  const float* rays_d = (const float*)d_in[1];
  const float* dW1 = (const float*)d_in[2];
  const float* db1 = (const float*)d_in[3];
  const float* dW2 = (const float*)d_in[4];
  const float* db2 = (const float*)d_in[5];
  const float* dW3 = (const float*)d_in[6];
  const float* db3 = (const float*)d_in[7];
  const float* cW1 = (const float*)d_in[8];
  const float* cb1 = (const float*)d_in[9];
  const float* cW2 = (const float*)d_in[10];
  const float* cb2 = (const float*)d_in[11];
  const float* cW3 = (const float*)d_in[12];
  const float* cb3 = (const float*)d_in[13];
  // num_steps / upsample_steps fixed at 128/128 (compile-time).

  char* ws = (char*)d_ws;
  size_t off = 0;
  auto alloc = [&](size_t bytes) -> void* {
    void* p = ws + off;
    off += (bytes + 255) & ~(size_t)255;
    return p;
  };
  unsigned short* Wp_d1 = (unsigned short*)alloc(8192 * 2);
  unsigned short* Wp_d2 = (unsigned short*)alloc(65536 * 2);
  unsigned short* Wp_d3 = (unsigned short*)alloc(4096 * 2);
  unsigned short* Wp_c1 = (unsigned short*)alloc(8192 * 2);
  unsigned short* Wp_c2 = (unsigned short*)alloc(65536 * 2);
  unsigned short* Wp_c3 = (unsigned short*)alloc(4096 * 2);
  float* z_c  = (float*)alloc((size_t)NRAYS * NSTEP * 4);
  float* z_f  = (float*)alloc((size_t)NRAYS * NSTEP * 4);
  float* o16c = (float*)alloc((size_t)NRAYS * NSTEP * 16 * 4);
  float* o16f = (float*)alloc((size_t)NRAYS * NSTEP * 16 * 4);
  float* z_m  = (float*)alloc((size_t)NRAYS * TSAMP * 4);
  int*   ordr = (int*)alloc((size_t)NRAYS * TSAMP * 4);
  float* wgt  = (float*)alloc((size_t)NRAYS * TSAMP * 4);
  float* rgb4 = (float*)alloc((size_t)NRAYS * TSAMP * 4 * 4);
  (void)ws_size; (void)in_sizes; (void)n_in; (void)out_size;

  k_pack<<<8192 / 256, 256, 0, stream>>>(dW1, Wp_d1, 3, 256, 16, 8192);
  k_pack<<<65536 / 256, 256, 0, stream>>>(dW2, Wp_d2, 256, 256, 16, 65536);
  k_pack<<<4096 / 256, 256, 0, stream>>>(dW3, Wp_d3, 256, 16, 1, 4096);
  k_pack_c1<<<8192 / 256, 256, 0, stream>>>(cW1, Wp_c1);
  k_pack<<<65536 / 256, 256, 0, stream>>>(cW2, Wp_c2, 256, 256, 16, 65536);
  k_pack<<<4096 / 256, 256, 0, stream>>>(cW3, Wp_c3, 256, 3, 1, 4096);

  k_raysetup<<<NRAYS, 128, 0, stream>>>(rays_o, rays_d, z_c);
  k_density<<<(NRAYS * NSTEP) / (64 * DTPW), 256, 0, stream>>>(
      rays_o, rays_d, z_c, Wp_d1, db1, Wp_d2, db2, Wp_d3, db3, o16c);
  k_pdf<<<NRAYS, 128, 0, stream>>>(z_c, o16c, z_f);
  k_density<<<(NRAYS * NSTEP) / (64 * DTPW), 256, 0, stream>>>(
      rays_o, rays_d, z_f, Wp_d1, db1, Wp_d2, db2, Wp_d3, db3, o16f);
  k_merge<<<NRAYS, 256, 0, stream>>>(z_c, z_f, o16c, o16f, z_m, ordr, wgt);
  k_color<<<(NRAYS * TSAMP) / (64 * CTPW), 256, 0, stream>>>(
      rays_d, ordr, wgt, o16c, o16f, Wp_c1, cb1, Wp_c2, cb2, Wp_c3, cb3, rgb4);
  k_final<<<NRAYS, 256, 0, stream>>>(z_m, wgt, rgb4, (float*)d_out);
}

// Round 5
// 441.769 us; speedup vs baseline: 1.2163x; 1.2163x over previous
//
#include <hip/hip_runtime.h>

// NeRF renderer pipeline for MI355X (gfx950).
// R5: R4's register-resident weights spilled: launch_bounds(256,2) capped the
// unified RF at 256, LLVM demoted the whole w2r array to scratch (VGPR=128,
// WRITE_SIZE 96MB). Fix: no launch_bounds floor (512-reg budget), W1 streamed
// per tile, tile loop unroll-disabled. Also: out16 split into sig (fp32) +
// gout (bf16 geo) -> coalesced sigma reads in pdf/merge, conversion-free
// color gather.

typedef float f32x4 __attribute__((ext_vector_type(4)));
typedef __bf16 bf16x8 __attribute__((ext_vector_type(8)));
typedef unsigned short u16x8 __attribute__((ext_vector_type(8)));
typedef unsigned short u16x4 __attribute__((ext_vector_type(4)));

#define NRAYS 2048
#define NSTEP 128
#define TSAMP 256
#define MIN_NEAR 0.05f
#define DTPW 4   // density tiles (64 pts) per workgroup
#define CTPW 4   // color tiles per workgroup

__device__ __forceinline__ unsigned short f2bf(float f) {
  unsigned int u = __float_as_uint(f);
  u += 0x7FFFu + ((u >> 16) & 1u);   // round-to-nearest-even
  return (unsigned short)(u >> 16);
}

// ---------------------------------------------------------------- weight pack
// dst[((kt*NT+nt)*64+lane)*8+j] = W[k][n], k=kt*32+(lane>>4)*8+j, n=nt*16+(lane&15)
// A-operand frag of the swapped layer: A[m=n][k] = W[k][n].
__global__ void k_pack(const float* __restrict__ W, unsigned short* __restrict__ dst,
                       int K, int Norig, int NT, int total) {
  int idx = blockIdx.x * 256 + threadIdx.x;
  if (idx >= total) return;
  int per = NT * 512;
  int kt = idx / per;
  int rm = idx % per;
  int nt = rm >> 9;
  int lane = (rm >> 3) & 63;
  int j = rm & 7;
  int k = kt * 32 + ((lane >> 4) << 3) + j;
  int n = nt * 16 + (lane & 15);
  float v = (k < K && n < Norig) ? W[k * Norig + n] : 0.0f;
  dst[idx] = f2bf(v);
}

// Density L3 pack with output permutation: feature f -> dW3 col (f+1)&15,
// so features 0..14 = geo0..14, feature 15 = sigma.
__global__ void k_pack_d3(const float* __restrict__ dW3, unsigned short* __restrict__ dst) {
  int idx = blockIdx.x * 256 + threadIdx.x;  // total 4096
  int lane = (idx >> 3) & 63;
  int j = idx & 7;
  int kt = idx >> 9;
  int k = kt * 32 + ((lane >> 4) << 3) + j;
  int n = lane & 15;
  dst[idx] = f2bf(dW3[k * 16 + ((n + 1) & 15)]);
}

// Color L1 pack, input layout X = [geo0..14, 0, dir0..2, 0...]:
// k 0..14 -> cW1 row 3+k (geo); k 16..18 -> rows 0..2 (dir); else 0.
__global__ void k_pack_c1(const float* __restrict__ cW1, unsigned short* __restrict__ dst) {
  int idx = blockIdx.x * 256 + threadIdx.x;  // total 8192
  int nt = idx >> 9;
  int lane = (idx >> 3) & 63;
  int j = idx & 7;
  int k = ((lane >> 4) << 3) + j;   // 0..31
  int n = nt * 16 + (lane & 15);
  float v = 0.0f;
  if (k < 15) v = cW1[(3 + k) * 256 + n];
  else if (k >= 16 && k < 19) v = cW1[(k - 16) * 256 + n];
  dst[idx] = f2bf(v);
}

// ---------------------------------------------------------------- ray setup
__global__ void k_raysetup(const float* __restrict__ o, const float* __restrict__ d,
                           float* __restrict__ z_c) {
  int r = blockIdx.x, i = threadIdx.x;  // 128 threads
  float ox = o[r * 3], oy = o[r * 3 + 1], oz = o[r * 3 + 2];
  float dx = d[r * 3], dy = d[r * 3 + 1], dz = d[r * 3 + 2];
  float b = ox * dx + oy * dy + oz * dz;
  float c = ox * ox + oy * oy + oz * oz - 1.0f;
  float disc = fmaxf(b * b - c, 0.0f);
  float zmax = fmaxf(-b + sqrtf(disc), MIN_NEAR + 1e-3f);
  float zmin = MIN_NEAR;
  float t = (float)i / 127.0f;
  float z = zmin + (zmax - zmin) * t;
  z = fminf(fmaxf(z, zmin), zmax);
  z_c[r * NSTEP + i] = z;
}

// ---------------------------------------------------------------- density MLP
// LDS act layout: h[p][n] at u16 offset p*256 + ((n>>3)^(p&31))*8 + (n&7)
// xb layout: X[p][c] at u16 offset p*32 + ((g^(p&3))*8) + (c&7), g=c>>3
__global__ __launch_bounds__(256)
void k_density(const float* __restrict__ rays_o, const float* __restrict__ rays_d,
               const float* __restrict__ z,
               const unsigned short* __restrict__ Wp1, const float* __restrict__ b1,
               const unsigned short* __restrict__ Wp2, const float* __restrict__ b2,
               const unsigned short* __restrict__ Wp3, const float* __restrict__ b3,
               unsigned short* __restrict__ gout, float* __restrict__ sig) {
  __shared__ unsigned short buf[64 * 256];
  __shared__ unsigned short xb[64 * 32];
  const int t = threadIdx.x;
  const int lane = t & 63;
  const int wid = t >> 6;
  const int quad = lane >> 4;
  const int col = lane & 15;

  // one-time register-resident W2 slice (wave's 64 features, full K)
  bf16x8 w2r[8][4];
#pragma unroll
  for (int kt = 0; kt < 8; ++kt)
#pragma unroll
    for (int ntl = 0; ntl < 4; ++ntl)
      w2r[kt][ntl] = *reinterpret_cast<const bf16x8*>(Wp2 + ((kt * 16 + wid * 4 + ntl) * 64 + lane) * 8);

#pragma unroll 1
  for (int tt = 0; tt < DTPW; ++tt) {
    const int P0 = (blockIdx.x * DTPW + tt) * 64;
    // W1 slice streamed per tile (loop-invariant value, short live range)
    bf16x8 w1s[4];
#pragma unroll
    for (int ntl = 0; ntl < 4; ++ntl)
      w1s[ntl] = *reinterpret_cast<const bf16x8*>(Wp1 + ((wid * 4 + ntl) * 64 + lane) * 8);
    { // build X = [x,y,z,0..] bf16 rows (4 threads/point, one u16x8 each)
      int p = t >> 2, g = t & 3;
      int P = P0 + p, r = P >> 7;
      u16x8 pk = {0, 0, 0, 0, 0, 0, 0, 0};
      if (g == 0) {
        float zz = z[P];
        pk[0] = f2bf(rays_o[r * 3 + 0] + rays_d[r * 3 + 0] * zz);
        pk[1] = f2bf(rays_o[r * 3 + 1] + rays_d[r * 3 + 1] * zz);
        pk[2] = f2bf(rays_o[r * 3 + 2] + rays_d[r * 3 + 2] * zz);
      }
      *reinterpret_cast<u16x8*>(&xb[p * 32 + ((g ^ (p & 3)) * 8)]) = pk;
    }
    __syncthreads();  // B1: xb ready; prev tile's L3 buf-reads retired
    { // L1: K=32 MFMA, h1 -> buf
      f32x4 acc[16];
#pragma unroll
      for (int i = 0; i < 16; ++i) acc[i] = (f32x4){0.f, 0.f, 0.f, 0.f};
      bf16x8 x[4];
#pragma unroll
      for (int pt = 0; pt < 4; ++pt) {
        int p = pt * 16 + col;
        x[pt] = *reinterpret_cast<const bf16x8*>(&xb[p * 32 + ((quad ^ (p & 3)) * 8)]);
      }
#pragma unroll
      for (int ntl = 0; ntl < 4; ++ntl)
#pragma unroll
        for (int pt = 0; pt < 4; ++pt)
          acc[ntl * 4 + pt] = __builtin_amdgcn_mfma_f32_16x16x32_bf16(w1s[ntl], x[pt], acc[ntl * 4 + pt], 0, 0, 0);
#pragma unroll
      for (int ntl = 0; ntl < 4; ++ntl) {
        int n = (wid * 4 + ntl) * 16 + quad * 4;
        f32x4 bv = *reinterpret_cast<const f32x4*>(b1 + n);
#pragma unroll
        for (int pt = 0; pt < 4; ++pt) {
          int p = pt * 16 + col;
          u16x4 pk;
#pragma unroll
          for (int rr = 0; rr < 4; ++rr)
            pk[rr] = f2bf(fmaxf(acc[ntl * 4 + pt][rr] + bv[rr], 0.0f));
          *reinterpret_cast<u16x4*>(&buf[p * 256 + (((n >> 3) ^ (p & 31)) * 8) + (n & 7)]) = pk;
        }
      }
    }
    __syncthreads();  // B2: h1 complete
    { // L2: 256x256, weights in registers, x streamed from LDS
      f32x4 acc[16];
#pragma unroll
      for (int i = 0; i < 16; ++i) acc[i] = (f32x4){0.f, 0.f, 0.f, 0.f};
#pragma unroll
      for (int kt = 0; kt < 8; ++kt) {
        bf16x8 x[4];
#pragma unroll
        for (int pt = 0; pt < 4; ++pt) {
          int p = pt * 16 + col;
          x[pt] = *reinterpret_cast<const bf16x8*>(&buf[p * 256 + (((kt * 4 + quad) ^ (p & 31)) * 8)]);
        }
#pragma unroll
        for (int ntl = 0; ntl < 4; ++ntl)
#pragma unroll
          for (int pt = 0; pt < 4; ++pt)
            acc[ntl * 4 + pt] = __builtin_amdgcn_mfma_f32_16x16x32_bf16(w2r[kt][ntl], x[pt], acc[ntl * 4 + pt], 0, 0, 0);
      }
      __syncthreads();  // B3: all buf reads done before in-place overwrite
#pragma unroll
      for (int ntl = 0; ntl < 4; ++ntl) {
        int n = (wid * 4 + ntl) * 16 + quad * 4;
        f32x4 bv = *reinterpret_cast<const f32x4*>(b2 + n);
#pragma unroll
        for (int pt = 0; pt < 4; ++pt) {
          int p = pt * 16 + col;
          u16x4 pk;
#pragma unroll
          for (int rr = 0; rr < 4; ++rr)
            pk[rr] = f2bf(fmaxf(acc[ntl * 4 + pt][rr] + bv[rr], 0.0f));
          *reinterpret_cast<u16x4*>(&buf[p * 256 + (((n >> 3) ^ (p & 31)) * 8) + (n & 7)]) = pk;
        }
      }
    }
    __syncthreads();  // B4: h2 complete
    { // L3: 256 -> 16 permuted [geo15 | sigma]; wave wid owns p-tile wid
      const int p = wid * 16 + col;
      f32x4 acc = {0.f, 0.f, 0.f, 0.f};
#pragma unroll
      for (int kt = 0; kt < 8; ++kt) {
        bf16x8 w = *reinterpret_cast<const bf16x8*>(&Wp3[(kt * 64 + lane) * 8]);
        bf16x8 x = *reinterpret_cast<const bf16x8*>(&buf[p * 256 + (((kt * 4 + quad) ^ (p & 31)) * 8)]);
        acc = __builtin_amdgcn_mfma_f32_16x16x32_bf16(w, x, acc, 0, 0, 0);
      }
      int n0 = quad * 4;  // features n0..n0+3 of point p (permuted order)
      u16x4 pk;
#pragma unroll
      for (int rr = 0; rr < 4; ++rr) {
        float v = acc[rr] + b3[(n0 + rr + 1) & 15];
        if (quad == 3 && rr == 3) {  // sigma: trunc_exp -> sig[], gout slot = 0
          sig[P0 + p] = expf(fminf(fmaxf(v, -15.f), 15.f));
          pk[rr] = 0;
        } else {
          pk[rr] = f2bf(v);
        }
      }
      *reinterpret_cast<u16x4*>(gout + (size_t)(P0 + p) * 16 + n0) = pk;
    }
  }
}

// ------------------------------------------------- coarse weights + sample_pdf
__global__ void k_pdf(const float* __restrict__ z_c, const float* __restrict__ sigc,
                      float* __restrict__ z_f) {
  __shared__ float sz[128], sl[128], sw[128], scdf[128], szmid[128];
  int r = blockIdx.x, i = threadIdx.x;  // 128 threads
  float zi = z_c[r * NSTEP + i];
  sz[i] = zi;
  float sg = sigc[r * NSTEP + i];
  __syncthreads();
  float aug = (i < 127) ? (sz[i + 1] - zi) : (sz[127] - sz[126]);
  float alpha = 1.0f - expf(-aug * sg);
  float term = 1.0f - alpha + 1e-15f;
  sl[i] = logf(term);
  __syncthreads();
  for (int off = 1; off < 128; off <<= 1) {  // inclusive scan of log-terms
    float y = (i >= off) ? sl[i - off] : 0.0f;
    __syncthreads();
    sl[i] += y;
    __syncthreads();
  }
  float excl = (i > 0) ? sl[i - 1] : 0.0f;
  float w = alpha * expf(excl);
  sw[i] = w;
  __syncthreads();
  float v = (i < 126) ? (sw[i + 1] + 1e-5f) : 0.0f;  // weights[:,1:-1] + 1e-5
  sl[i] = v;
  __syncthreads();
  for (int off = 1; off < 128; off <<= 1) {
    float y = (i >= off) ? sl[i - off] : 0.0f;
    __syncthreads();
    sl[i] += y;
    __syncthreads();
  }
  float total = sl[125];
  if (i <= 126) scdf[i] = (i == 0) ? 0.0f : sl[i - 1] / total;
  if (i < 127) szmid[i] = 0.5f * (sz[i] + sz[i + 1]);
  __syncthreads();
  const float lo = 0.5f / 128.0f, hi = 1.0f - 0.5f / 128.0f;
  float u = lo + (hi - lo) * ((float)i / 127.0f);
  int loI = 0, hiI = 127;  // searchsorted right over scdf[0..126]
  while (loI < hiI) {
    int mid = (loI + hiI) >> 1;
    if (scdf[mid] > u) hiI = mid; else loI = mid + 1;
  }
  int inds = loI;
  int below = inds - 1; if (below < 0) below = 0; if (below > 126) below = 126;
  int above = inds; if (above > 126) above = 126;
  float c0 = scdf[below], c1 = scdf[above];
  float b0 = szmid[below], b1 = szmid[above];
  float dn = c1 - c0; if (dn < 1e-5f) dn = 1.0f;
  float tt = (u - c0) / dn;
  z_f[r * NSTEP + i] = b0 + tt * (b1 - b0);
}

// ---------------------------------------------- merge (stable) + final weights
__global__ void k_merge(const float* __restrict__ z_c, const float* __restrict__ z_f,
                        const float* __restrict__ sigc, const float* __restrict__ sigf,
                        float* __restrict__ z_m, int* __restrict__ order,
                        float* __restrict__ wgt) {
  __shared__ float szc[128], szf[128], szm[256], sl[256];
  __shared__ int sord[256];
  int r = blockIdx.x, t = threadIdx.x;  // 256 threads
  if (t < 128) szc[t] = z_c[r * NSTEP + t];
  else szf[t - 128] = z_f[r * NSTEP + t - 128];
  __syncthreads();
  int pos; float myz;
  if (t < 128) {  // coarse i: pos = i + #{zf < zc[i]}   (ties: coarse first)
    myz = szc[t];
    int lo = 0, hi = 128;
    while (lo < hi) { int m = (lo + hi) >> 1; if (szf[m] < myz) lo = m + 1; else hi = m; }
    pos = t + lo;
  } else {        // fine j: pos = j + #{zc <= zf[j]}
    int j = t - 128; myz = szf[j];
    int lo = 0, hi = 128;
    while (lo < hi) { int m = (lo + hi) >> 1; if (szc[m] <= myz) lo = m + 1; else hi = m; }
    pos = j + lo;
  }
  szm[pos] = myz; sord[pos] = t;
  __syncthreads();
  z_m[r * TSAMP + t] = szm[t];
  order[r * TSAMP + t] = sord[t];
  int src = sord[t];
  float sg = (src < 128) ? sigc[r * NSTEP + src] : sigf[r * NSTEP + (src - 128)];
  float zt = szm[t];
  float aug = (t < 255) ? (szm[t + 1] - zt) : (szm[255] - szm[254]);
  float alpha = 1.0f - expf(-aug * sg);
  sl[t] = logf(1.0f - alpha + 1e-15f);
  __syncthreads();
  for (int off = 1; off < 256; off <<= 1) {
    float y = (t >= off) ? sl[t - off] : 0.0f;
    __syncthreads();
    sl[t] += y;
    __syncthreads();
  }
  float excl = (t > 0) ? sl[t - 1] : 0.0f;
  wgt[r * TSAMP + t] = alpha * expf(excl);
}

// ---------------------------------------------------------------- color MLP
__global__ __launch_bounds__(256)
void k_color(const float* __restrict__ rays_d, const int* __restrict__ order,
             const float* __restrict__ wgt,
             const unsigned short* __restrict__ goutc, const unsigned short* __restrict__ goutf,
             const unsigned short* __restrict__ Wp1, const float* __restrict__ cb1,
             const unsigned short* __restrict__ Wp2, const float* __restrict__ cb2,
             const unsigned short* __restrict__ Wp3, const float* __restrict__ cb3,
             float* __restrict__ rgb4) {
  __shared__ unsigned short buf[64 * 256];
  __shared__ unsigned short xb[64 * 32];
  const int t = threadIdx.x;
  const int lane = t & 63;
  const int wid = t >> 6;
  const int quad = lane >> 4;
  const int col = lane & 15;

  bf16x8 w2r[8][4];
#pragma unroll
  for (int kt = 0; kt < 8; ++kt)
#pragma unroll
    for (int ntl = 0; ntl < 4; ++ntl)
      w2r[kt][ntl] = *reinterpret_cast<const bf16x8*>(Wp2 + ((kt * 16 + wid * 4 + ntl) * 64 + lane) * 8);

#pragma unroll 1
  for (int tt = 0; tt < CTPW; ++tt) {
    const int P0 = (blockIdx.x * CTPW + tt) * 64;
    int pred = 0;
    { // X = [geo0..14, 0, dir, 0...] (4 threads/point, u16x8 each)
      int p = t >> 2, g = t & 3;
      int P = P0 + p, r = P >> 8;
      u16x8 pk = {0, 0, 0, 0, 0, 0, 0, 0};
      if (g < 2) {
        int src = order[P];
        const unsigned short* gsrc = (src < 128)
            ? (goutc + (size_t)(r * NSTEP + src) * 16)
            : (goutf + (size_t)(r * NSTEP + (src - 128)) * 16);
        pk = *reinterpret_cast<const u16x8*>(gsrc + g * 8);  // slot15 already 0
      } else if (g == 2) {
        pk[0] = f2bf(rays_d[r * 3 + 0]);
        pk[1] = f2bf(rays_d[r * 3 + 1]);
        pk[2] = f2bf(rays_d[r * 3 + 2]);
      } else {
        pred = (wgt[P] > 1e-4f) ? 1 : 0;
      }
      *reinterpret_cast<u16x8*>(&xb[p * 32 + ((g ^ (p & 3)) * 8)]) = pk;
    }
    if (!__syncthreads_or(pred)) continue;  // whole tile masked: rgb never read
    bf16x8 w1s[4];
#pragma unroll
    for (int ntl = 0; ntl < 4; ++ntl)
      w1s[ntl] = *reinterpret_cast<const bf16x8*>(Wp1 + ((wid * 4 + ntl) * 64 + lane) * 8);
    { // L1: K=32 MFMA, h1 -> buf
      f32x4 acc[16];
#pragma unroll
      for (int i = 0; i < 16; ++i) acc[i] = (f32x4){0.f, 0.f, 0.f, 0.f};
      bf16x8 x[4];
#pragma unroll
      for (int pt = 0; pt < 4; ++pt) {
        int p = pt * 16 + col;
        x[pt] = *reinterpret_cast<const bf16x8*>(&xb[p * 32 + ((quad ^ (p & 3)) * 8)]);
      }
#pragma unroll
      for (int ntl = 0; ntl < 4; ++ntl)
#pragma unroll
        for (int pt = 0; pt < 4; ++pt)
          acc[ntl * 4 + pt] = __builtin_amdgcn_mfma_f32_16x16x32_bf16(w1s[ntl], x[pt], acc[ntl * 4 + pt], 0, 0, 0);
#pragma unroll
      for (int ntl = 0; ntl < 4; ++ntl) {
        int n = (wid * 4 + ntl) * 16 + quad * 4;
        f32x4 bv = *reinterpret_cast<const f32x4*>(cb1 + n);
#pragma unroll
        for (int pt = 0; pt < 4; ++pt) {
          int p = pt * 16 + col;
          u16x4 pk;
#pragma unroll
          for (int rr = 0; rr < 4; ++rr)
            pk[rr] = f2bf(fmaxf(acc[ntl * 4 + pt][rr] + bv[rr], 0.0f));
          *reinterpret_cast<u16x4*>(&buf[p * 256 + (((n >> 3) ^ (p & 31)) * 8) + (n & 7)]) = pk;
        }
      }
    }
    __syncthreads();  // B2
    { // L2: 256x256, register weights
      f32x4 acc[16];
#pragma unroll
      for (int i = 0; i < 16; ++i) acc[i] = (f32x4){0.f, 0.f, 0.f, 0.f};
#pragma unroll
      for (int kt = 0; kt < 8; ++kt) {
        bf16x8 x[4];
#pragma unroll
        for (int pt = 0; pt < 4; ++pt) {
          int p = pt * 16 + col;
          x[pt] = *reinterpret_cast<const bf16x8*>(&buf[p * 256 + (((kt * 4 + quad) ^ (p & 31)) * 8)]);
        }
#pragma unroll
        for (int ntl = 0; ntl < 4; ++ntl)
#pragma unroll
          for (int pt = 0; pt < 4; ++pt)
            acc[ntl * 4 + pt] = __builtin_amdgcn_mfma_f32_16x16x32_bf16(w2r[kt][ntl], x[pt], acc[ntl * 4 + pt], 0, 0, 0);
      }
      __syncthreads();  // B3
#pragma unroll
      for (int ntl = 0; ntl < 4; ++ntl) {
        int n = (wid * 4 + ntl) * 16 + quad * 4;
        f32x4 bv = *reinterpret_cast<const f32x4*>(cb2 + n);
#pragma unroll
        for (int pt = 0; pt < 4; ++pt) {
          int p = pt * 16 + col;
          u16x4 pk;
#pragma unroll
          for (int rr = 0; rr < 4; ++rr)
            pk[rr] = f2bf(fmaxf(acc[ntl * 4 + pt][rr] + bv[rr], 0.0f));
          *reinterpret_cast<u16x4*>(&buf[p * 256 + (((n >> 3) ^ (p & 31)) * 8) + (n & 7)]) = pk;
        }
      }
    }
    __syncthreads();  // B4
    { // L3: 256 -> 3 (padded 16), sigmoid; wave wid owns p-tile wid
      const int p = wid * 16 + col;
      f32x4 acc = {0.f, 0.f, 0.f, 0.f};
#pragma unroll
      for (int kt = 0; kt < 8; ++kt) {
        bf16x8 w = *reinterpret_cast<const bf16x8*>(&Wp3[(kt * 64 + lane) * 8]);
        bf16x8 x = *reinterpret_cast<const bf16x8*>(&buf[p * 256 + (((kt * 4 + quad) ^ (p & 31)) * 8)]);
        acc = __builtin_amdgcn_mfma_f32_16x16x32_bf16(w, x, acc, 0, 0, 0);
      }
      if (quad == 0) {
        f32x4 v;
#pragma unroll
        for (int rr = 0; rr < 3; ++rr) {
          float s = acc[rr] + cb3[rr];
          v[rr] = 1.0f / (1.0f + expf(-s));
        }
        v[3] = 0.0f;
        *reinterpret_cast<f32x4*>(rgb4 + (size_t)(P0 + p) * 4) = v;
      }
    }
    __syncthreads();  // L3 buf reads done before next tile's L1 writes
  }
}

// ------------------------------------------------------- final per-ray outputs
__device__ __forceinline__ float block_reduce(float v, float* s, int t) {
  s[t] = v;
  __syncthreads();
  for (int off = 128; off > 0; off >>= 1) {
    if (t < off) s[t] += s[t + off];
    __syncthreads();
  }
  float r = s[0];
  __syncthreads();
  return r;
}

__global__ void k_final(const float* __restrict__ z_m, const float* __restrict__ wgt,
                        const float* __restrict__ rgb4, float* __restrict__ out) {
  __shared__ float sz[256], sw[256], smid[256], sred[256];
  int r = blockIdx.x, t = threadIdx.x;  // 256 threads
  float zt = z_m[r * TSAMP + t];
  float wt = wgt[r * TSAMP + t];
  sz[t] = zt; sw[t] = wt;
  __syncthreads();
  float znext = (t < 255) ? sz[t + 1] : (1.0f / 128.0f);  // sample_dist
  smid[t] = 0.5f * zt + 0.5f * znext;
  float cr = 0.f, cg = 0.f, cb = 0.f;
  if (wt > 1e-4f) {
    f32x4 c = *reinterpret_cast<const f32x4*>(rgb4 + (size_t)(r * TSAMP + t) * 4);
    cr = c[0]; cg = c[1]; cb = c[2];
  }
  __syncthreads();
  float mt = smid[t];
  float acc = 0.f;
  for (int j = 0; j < 256; ++j) acc += fabsf(mt - smid[j]) * sw[j];
  acc *= wt;
  float wsum = block_reduce(wt, sred, t);
  float depth = block_reduce(wt * zt, sred, t);
  float ir = block_reduce(wt * cr, sred, t);
  float ig = block_reduce(wt * cg, sred, t);
  float ib = block_reduce(wt * cb, sred, t);
  float S = block_reduce(acc, sred, t);
  if (t == 0) {
    const float bgc = 206.0f / 255.0f;
    float loss = S / (depth + 1e-6f);
    if (loss < 1e-3f) loss = 0.0f;
    out[r * 5 + 0] = ir + (1.0f - wsum) * bgc;
    out[r * 5 + 1] = ig + (1.0f - wsum) * bgc;
    out[r * 5 + 2] = ib + (1.0f - wsum) * bgc;
    out[r * 5 + 3] = depth;
    out[r * 5 + 4] = loss;
  }
}

// ---------------------------------------------------------------- launch
extern "C" void kernel_launch(void* const* d_in, const int* in_sizes, int n_in,
                              void* d_out, int out_size, void* d_ws, size_t ws_size,
                              hipStream_t stream) {
  const float* rays_o = (const float*)d_in[0];
  const float* rays_d = (const float*)d_in[1];
  const float* dW1 = (const float*)d_in[2];
  const float* db1 = (const float*)d_in[3];
  const float* dW2 = (const float*)d_in[4];
  const float* db2 = (const float*)d_in[5];
  const float* dW3 = (const float*)d_in[6];
  const float* db3 = (const float*)d_in[7];
  const float* cW1 = (const float*)d_in[8];
  const float* cb1 = (const float*)d_in[9];
  const float* cW2 = (const float*)d_in[10];
  const float* cb2 = (const float*)d_in[11];
  const float* cW3 = (const float*)d_in[12];
  const float* cb3 = (const float*)d_in[13];
  // num_steps / upsample_steps fixed at 128/128 (compile-time).

  char* ws = (char*)d_ws;
  size_t off = 0;
  auto alloc = [&](size_t bytes) -> void* {
    void* p = ws + off;
    off += (bytes + 255) & ~(size_t)255;
    return p;
  };
  unsigned short* Wp_d1 = (unsigned short*)alloc(8192 * 2);
  unsigned short* Wp_d2 = (unsigned short*)alloc(65536 * 2);
  unsigned short* Wp_d3 = (unsigned short*)alloc(4096 * 2);
  unsigned short* Wp_c1 = (unsigned short*)alloc(8192 * 2);
  unsigned short* Wp_c2 = (unsigned short*)alloc(65536 * 2);
  unsigned short* Wp_c3 = (unsigned short*)alloc(4096 * 2);
  float* z_c  = (float*)alloc((size_t)NRAYS * NSTEP * 4);
  float* z_f  = (float*)alloc((size_t)NRAYS * NSTEP * 4);
  unsigned short* goutc = (unsigned short*)alloc((size_t)NRAYS * NSTEP * 16 * 2);
  unsigned short* goutf = (unsigned short*)alloc((size_t)NRAYS * NSTEP * 16 * 2);
  float* sigc = (float*)alloc((size_t)NRAYS * NSTEP * 4);
  float* sigf = (float*)alloc((size_t)NRAYS * NSTEP * 4);
  float* z_m  = (float*)alloc((size_t)NRAYS * TSAMP * 4);
  int*   ordr = (int*)alloc((size_t)NRAYS * TSAMP * 4);
  float* wgt  = (float*)alloc((size_t)NRAYS * TSAMP * 4);
  float* rgb4 = (float*)alloc((size_t)NRAYS * TSAMP * 4 * 4);
  (void)ws_size; (void)in_sizes; (void)n_in; (void)out_size;

  k_pack<<<8192 / 256, 256, 0, stream>>>(dW1, Wp_d1, 3, 256, 16, 8192);
  k_pack<<<65536 / 256, 256, 0, stream>>>(dW2, Wp_d2, 256, 256, 16, 65536);
  k_pack_d3<<<4096 / 256, 256, 0, stream>>>(dW3, Wp_d3);
  k_pack_c1<<<8192 / 256, 256, 0, stream>>>(cW1, Wp_c1);
  k_pack<<<65536 / 256, 256, 0, stream>>>(cW2, Wp_c2, 256, 256, 16, 65536);
  k_pack<<<4096 / 256, 256, 0, stream>>>(cW3, Wp_c3, 256, 3, 1, 4096);

  k_raysetup<<<NRAYS, 128, 0, stream>>>(rays_o, rays_d, z_c);
  k_density<<<(NRAYS * NSTEP) / (64 * DTPW), 256, 0, stream>>>(
      rays_o, rays_d, z_c, Wp_d1, db1, Wp_d2, db2, Wp_d3, db3, goutc, sigc);
  k_pdf<<<NRAYS, 128, 0, stream>>>(z_c, sigc, z_f);
  k_density<<<(NRAYS * NSTEP) / (64 * DTPW), 256, 0, stream>>>(
      rays_o, rays_d, z_f, Wp_d1, db1, Wp_d2, db2, Wp_d3, db3, goutf, sigf);
  k_merge<<<NRAYS, 256, 0, stream>>>(z_c, z_f, sigc, sigf, z_m, ordr, wgt);
  k_color<<<(NRAYS * TSAMP) / (64 * CTPW), 256, 0, stream>>>(
      rays_d, ordr, wgt, goutc, goutf, Wp_c1, cb1, Wp_c2, cb2, Wp_c3, cb3, rgb4);
  k_final<<<NRAYS, 256, 0, stream>>>(z_m, wgt, rgb4, (float*)d_out);
}

// Round 6
// 308.920 us; speedup vs baseline: 1.7394x; 1.4300x over previous
//
#include <hip/hip_runtime.h>

// NeRF renderer pipeline for MI355X (gfx950).
// R6: R5's k_color ran at ~1 wave/SIMD (VGPR 164 arch + 64 acc AGPR + hoisted
// frags > 256 unified). Fix: (1) L1/L2 in two 32-point half-passes -> acc 32
// regs; (2) Wp3 + biases staged in LDS (no LICM reg pressure); (3)
// launch_bounds(256,2) enforced -> 2 waves/SIMD, 2 WG/CU; (4) gather/z
// prefetched one tile ahead (order->gout 2-level chain overlapped with MFMA).

typedef float f32x4 __attribute__((ext_vector_type(4)));
typedef __bf16 bf16x8 __attribute__((ext_vector_type(8)));
typedef unsigned short u16x8 __attribute__((ext_vector_type(8)));
typedef unsigned short u16x4 __attribute__((ext_vector_type(4)));

#define NRAYS 2048
#define NSTEP 128
#define TSAMP 256
#define MIN_NEAR 0.05f
#define DTPW 4   // density tiles (64 pts) per workgroup
#define CTPW 4   // color tiles per workgroup

__device__ __forceinline__ unsigned short f2bf(float f) {
  unsigned int u = __float_as_uint(f);
  u += 0x7FFFu + ((u >> 16) & 1u);   // round-to-nearest-even
  return (unsigned short)(u >> 16);
}

// ---------------------------------------------------------------- weight pack
// dst[((kt*NT+nt)*64+lane)*8+j] = W[k][n], k=kt*32+(lane>>4)*8+j, n=nt*16+(lane&15)
// A-operand frag of the swapped layer: A[m=n][k] = W[k][n].
__global__ void k_pack(const float* __restrict__ W, unsigned short* __restrict__ dst,
                       int K, int Norig, int NT, int total) {
  int idx = blockIdx.x * 256 + threadIdx.x;
  if (idx >= total) return;
  int per = NT * 512;
  int kt = idx / per;
  int rm = idx % per;
  int nt = rm >> 9;
  int lane = (rm >> 3) & 63;
  int j = rm & 7;
  int k = kt * 32 + ((lane >> 4) << 3) + j;
  int n = nt * 16 + (lane & 15);
  float v = (k < K && n < Norig) ? W[k * Norig + n] : 0.0f;
  dst[idx] = f2bf(v);
}

// Density L3 pack, output permuted: packed feature f -> dW3 col (f+1)&15,
// so features 0..14 = geo0..14, feature 15 = sigma.
__global__ void k_pack_d3(const float* __restrict__ dW3, unsigned short* __restrict__ dst) {
  int idx = blockIdx.x * 256 + threadIdx.x;  // total 4096
  int lane = (idx >> 3) & 63;
  int j = idx & 7;
  int kt = idx >> 9;
  int k = kt * 32 + ((lane >> 4) << 3) + j;
  int n = lane & 15;
  dst[idx] = f2bf(dW3[k * 16 + ((n + 1) & 15)]);
}

// Color L1 pack, input layout X = [geo0..14, 0, dir0..2, 0...]:
// k 0..14 -> cW1 row 3+k (geo); k 16..18 -> rows 0..2 (dir); else 0.
__global__ void k_pack_c1(const float* __restrict__ cW1, unsigned short* __restrict__ dst) {
  int idx = blockIdx.x * 256 + threadIdx.x;  // total 8192
  int nt = idx >> 9;
  int lane = (idx >> 3) & 63;
  int j = idx & 7;
  int k = ((lane >> 4) << 3) + j;   // 0..31
  int n = nt * 16 + (lane & 15);
  float v = 0.0f;
  if (k < 15) v = cW1[(3 + k) * 256 + n];
  else if (k >= 16 && k < 19) v = cW1[(k - 16) * 256 + n];
  dst[idx] = f2bf(v);
}

// ---------------------------------------------------------------- ray setup
__global__ void k_raysetup(const float* __restrict__ o, const float* __restrict__ d,
                           float* __restrict__ z_c) {
  int r = blockIdx.x, i = threadIdx.x;  // 128 threads
  float ox = o[r * 3], oy = o[r * 3 + 1], oz = o[r * 3 + 2];
  float dx = d[r * 3], dy = d[r * 3 + 1], dz = d[r * 3 + 2];
  float b = ox * dx + oy * dy + oz * dz;
  float c = ox * ox + oy * oy + oz * oz - 1.0f;
  float disc = fmaxf(b * b - c, 0.0f);
  float zmax = fmaxf(-b + sqrtf(disc), MIN_NEAR + 1e-3f);
  float zmin = MIN_NEAR;
  float t = (float)i / 127.0f;
  float z = zmin + (zmax - zmin) * t;
  z = fminf(fmaxf(z, zmin), zmax);
  z_c[r * NSTEP + i] = z;
}

// ---------------------------------------------------------------- MFMA helpers
// LDS act layout: h[p][n] at u16 offset p*256 + ((n>>3)^(p&31))*8 + (n&7)
// xb layout: X[p][c] at u16 offset p*32 + ((g^(p&3))*8) + (c&7), g=c>>3

// L1 (K=32): both halves, no internal barriers (xb != buf). acc 32 regs.
__device__ __forceinline__ void mlp_l1(const unsigned short* xb, unsigned short* buf,
                                       const bf16x8 (&w1r)[4], const float* sb1,
                                       int wid, int quad, int col) {
#pragma unroll
  for (int h = 0; h < 2; ++h) {
    f32x4 acc[8];
#pragma unroll
    for (int i = 0; i < 8; ++i) acc[i] = (f32x4){0.f, 0.f, 0.f, 0.f};
    int p0 = (h * 2) * 16 + col, p1 = (h * 2 + 1) * 16 + col;
    bf16x8 x0 = *reinterpret_cast<const bf16x8*>(&xb[p0 * 32 + ((quad ^ (p0 & 3)) * 8)]);
    bf16x8 x1 = *reinterpret_cast<const bf16x8*>(&xb[p1 * 32 + ((quad ^ (p1 & 3)) * 8)]);
#pragma unroll
    for (int ntl = 0; ntl < 4; ++ntl) {
      acc[ntl * 2 + 0] = __builtin_amdgcn_mfma_f32_16x16x32_bf16(w1r[ntl], x0, acc[ntl * 2 + 0], 0, 0, 0);
      acc[ntl * 2 + 1] = __builtin_amdgcn_mfma_f32_16x16x32_bf16(w1r[ntl], x1, acc[ntl * 2 + 1], 0, 0, 0);
    }
#pragma unroll
    for (int ntl = 0; ntl < 4; ++ntl) {
      int n = (wid * 4 + ntl) * 16 + quad * 4;
      f32x4 bv = *reinterpret_cast<const f32x4*>(&sb1[n]);
#pragma unroll
      for (int j = 0; j < 2; ++j) {
        int p = (h * 2 + j) * 16 + col;
        u16x4 pk;
#pragma unroll
        for (int rr = 0; rr < 4; ++rr)
          pk[rr] = f2bf(fmaxf(acc[ntl * 2 + j][rr] + bv[rr], 0.0f));
        *reinterpret_cast<u16x4*>(&buf[p * 256 + (((n >> 3) ^ (p & 31)) * 8) + (n & 7)]) = pk;
      }
    }
  }
}

// L2 (256x256) half-pass: reads rows [h*32, h*32+32) of old h1. Caller places
// __syncthreads() between compute (reads) and write (in-place overwrite).
__device__ __forceinline__ void l2_half_compute(const unsigned short* buf,
                                                const bf16x8 (&w2r)[8][4],
                                                f32x4 (&acc)[8], int h, int quad, int col) {
#pragma unroll
  for (int i = 0; i < 8; ++i) acc[i] = (f32x4){0.f, 0.f, 0.f, 0.f};
#pragma unroll
  for (int kt = 0; kt < 8; ++kt) {
    int p0 = (h * 2) * 16 + col, p1 = (h * 2 + 1) * 16 + col;
    bf16x8 x0 = *reinterpret_cast<const bf16x8*>(&buf[p0 * 256 + (((kt * 4 + quad) ^ (p0 & 31)) * 8)]);
    bf16x8 x1 = *reinterpret_cast<const bf16x8*>(&buf[p1 * 256 + (((kt * 4 + quad) ^ (p1 & 31)) * 8)]);
#pragma unroll
    for (int ntl = 0; ntl < 4; ++ntl) {
      acc[ntl * 2 + 0] = __builtin_amdgcn_mfma_f32_16x16x32_bf16(w2r[kt][ntl], x0, acc[ntl * 2 + 0], 0, 0, 0);
      acc[ntl * 2 + 1] = __builtin_amdgcn_mfma_f32_16x16x32_bf16(w2r[kt][ntl], x1, acc[ntl * 2 + 1], 0, 0, 0);
    }
  }
}

__device__ __forceinline__ void l2_half_write(unsigned short* buf, const f32x4 (&acc)[8],
                                              const float* sb2, int h, int wid, int quad, int col) {
#pragma unroll
  for (int ntl = 0; ntl < 4; ++ntl) {
    int n = (wid * 4 + ntl) * 16 + quad * 4;
    f32x4 bv = *reinterpret_cast<const f32x4*>(&sb2[n]);
#pragma unroll
    for (int j = 0; j < 2; ++j) {
      int p = (h * 2 + j) * 16 + col;
      u16x4 pk;
#pragma unroll
      for (int rr = 0; rr < 4; ++rr)
        pk[rr] = f2bf(fmaxf(acc[ntl * 2 + j][rr] + bv[rr], 0.0f));
      *reinterpret_cast<u16x4*>(&buf[p * 256 + (((n >> 3) ^ (p & 31)) * 8) + (n & 7)]) = pk;
    }
  }
}

// ---------------------------------------------------------------- density MLP
__global__ __launch_bounds__(256, 2)
void k_density(const float* __restrict__ rays_o, const float* __restrict__ rays_d,
               const float* __restrict__ z,
               const unsigned short* __restrict__ Wp1, const float* __restrict__ b1,
               const unsigned short* __restrict__ Wp2, const float* __restrict__ b2,
               const unsigned short* __restrict__ Wp3, const float* __restrict__ b3,
               unsigned short* __restrict__ gout, float* __restrict__ sig) {
  __shared__ unsigned short buf[64 * 256];
  __shared__ unsigned short xb[64 * 32];
  __shared__ unsigned short sW3[4096];
  __shared__ __align__(16) float sb1[256];
  __shared__ __align__(16) float sb2[256];
  __shared__ float sb3[16];
  const int t = threadIdx.x;
  const int lane = t & 63, wid = t >> 6, quad = lane >> 4, col = lane & 15;
  const int p_ = t >> 2, g_ = t & 3;

  sb1[t] = b1[t];
  sb2[t] = b2[t];
  if (t < 16) sb3[t] = b3[(t + 1) & 15];  // permuted to match k_pack_d3
  { const u16x8* s = (const u16x8*)Wp3; u16x8* d = (u16x8*)sW3;
    d[t] = s[t]; d[t + 256] = s[t + 256]; }

  bf16x8 w1r[4], w2r[8][4];
#pragma unroll
  for (int ntl = 0; ntl < 4; ++ntl)
    w1r[ntl] = *reinterpret_cast<const bf16x8*>(Wp1 + ((wid * 4 + ntl) * 64 + lane) * 8);
#pragma unroll
  for (int kt = 0; kt < 8; ++kt)
#pragma unroll
    for (int ntl = 0; ntl < 4; ++ntl)
      w2r[kt][ntl] = *reinterpret_cast<const bf16x8*>(Wp2 + ((kt * 16 + wid * 4 + ntl) * 64 + lane) * 8);

  float zv = z[blockIdx.x * DTPW * 64 + p_];  // prefetch tile 0

#pragma unroll 1
  for (int tt = 0; tt < DTPW; ++tt) {
    const int P0 = (blockIdx.x * DTPW + tt) * 64;
    { // build X = [x,y,z,0..]
      u16x8 pk = {0, 0, 0, 0, 0, 0, 0, 0};
      if (g_ == 0) {
        int r = (P0 + p_) >> 7;
        pk[0] = f2bf(rays_o[r * 3 + 0] + rays_d[r * 3 + 0] * zv);
        pk[1] = f2bf(rays_o[r * 3 + 1] + rays_d[r * 3 + 1] * zv);
        pk[2] = f2bf(rays_o[r * 3 + 2] + rays_d[r * 3 + 2] * zv);
      }
      *reinterpret_cast<u16x8*>(&xb[p_ * 32 + ((g_ ^ (p_ & 3)) * 8)]) = pk;
    }
    __syncthreads();  // xb ready; prev tile's L3 buf-reads retired
    mlp_l1(xb, buf, w1r, sb1, wid, quad, col);
    __syncthreads();  // B2: h1 complete
    float zn = 0.0f;
    if (tt + 1 < DTPW) zn = z[P0 + 64 + p_];  // prefetch next tile's z
    f32x4 acc[8];
    l2_half_compute(buf, w2r, acc, 0, quad, col);
    __syncthreads();  // all half0 reads done before overwrite
    l2_half_write(buf, acc, sb2, 0, wid, quad, col);
    l2_half_compute(buf, w2r, acc, 1, quad, col);
    __syncthreads();  // all half1 reads done
    l2_half_write(buf, acc, sb2, 1, wid, quad, col);
    __syncthreads();  // h2 complete
    { // L3: 256 -> 16 permuted [geo15 | sigma]; wave wid owns p-tile wid
      const int p = wid * 16 + col;
      f32x4 a3 = {0.f, 0.f, 0.f, 0.f};
#pragma unroll
      for (int kt = 0; kt < 8; ++kt) {
        bf16x8 w = *reinterpret_cast<const bf16x8*>(&sW3[(kt * 64 + lane) * 8]);
        bf16x8 x = *reinterpret_cast<const bf16x8*>(&buf[p * 256 + (((kt * 4 + quad) ^ (p & 31)) * 8)]);
        a3 = __builtin_amdgcn_mfma_f32_16x16x32_bf16(w, x, a3, 0, 0, 0);
      }
      int n0 = quad * 4;
      u16x4 pk;
#pragma unroll
      for (int rr = 0; rr < 4; ++rr) {
        float v = a3[rr] + sb3[n0 + rr];
        if (quad == 3 && rr == 3) {  // sigma: trunc_exp -> sig[], gout slot = 0
          sig[P0 + p] = expf(fminf(fmaxf(v, -15.f), 15.f));
          pk[rr] = 0;
        } else {
          pk[rr] = f2bf(v);
        }
      }
      *reinterpret_cast<u16x4*>(gout + (size_t)(P0 + p) * 16 + n0) = pk;
    }
    zv = zn;
  }
}

// ------------------------------------------------- coarse weights + sample_pdf
__global__ void k_pdf(const float* __restrict__ z_c, const float* __restrict__ sigc,
                      float* __restrict__ z_f) {
  __shared__ float sz[128], sl[128], sw[128], scdf[128], szmid[128];
  int r = blockIdx.x, i = threadIdx.x;  // 128 threads
  float zi = z_c[r * NSTEP + i];
  sz[i] = zi;
  float sg = sigc[r * NSTEP + i];
  __syncthreads();
  float aug = (i < 127) ? (sz[i + 1] - zi) : (sz[127] - sz[126]);
  float alpha = 1.0f - expf(-aug * sg);
  float term = 1.0f - alpha + 1e-15f;
  sl[i] = logf(term);
  __syncthreads();
  for (int off = 1; off < 128; off <<= 1) {  // inclusive scan of log-terms
    float y = (i >= off) ? sl[i - off] : 0.0f;
    __syncthreads();
    sl[i] += y;
    __syncthreads();
  }
  float excl = (i > 0) ? sl[i - 1] : 0.0f;
  float w = alpha * expf(excl);
  sw[i] = w;
  __syncthreads();
  float v = (i < 126) ? (sw[i + 1] + 1e-5f) : 0.0f;  // weights[:,1:-1] + 1e-5
  sl[i] = v;
  __syncthreads();
  for (int off = 1; off < 128; off <<= 1) {
    float y = (i >= off) ? sl[i - off] : 0.0f;
    __syncthreads();
    sl[i] += y;
    __syncthreads();
  }
  float total = sl[125];
  if (i <= 126) scdf[i] = (i == 0) ? 0.0f : sl[i - 1] / total;
  if (i < 127) szmid[i] = 0.5f * (sz[i] + sz[i + 1]);
  __syncthreads();
  const float lo = 0.5f / 128.0f, hi = 1.0f - 0.5f / 128.0f;
  float u = lo + (hi - lo) * ((float)i / 127.0f);
  int loI = 0, hiI = 127;  // searchsorted right over scdf[0..126]
  while (loI < hiI) {
    int mid = (loI + hiI) >> 1;
    if (scdf[mid] > u) hiI = mid; else loI = mid + 1;
  }
  int inds = loI;
  int below = inds - 1; if (below < 0) below = 0; if (below > 126) below = 126;
  int above = inds; if (above > 126) above = 126;
  float c0 = scdf[below], c1 = scdf[above];
  float b0 = szmid[below], b1 = szmid[above];
  float dn = c1 - c0; if (dn < 1e-5f) dn = 1.0f;
  float tt = (u - c0) / dn;
  z_f[r * NSTEP + i] = b0 + tt * (b1 - b0);
}

// ---------------------------------------------- merge (stable) + final weights
__global__ void k_merge(const float* __restrict__ z_c, const float* __restrict__ z_f,
                        const float* __restrict__ sigc, const float* __restrict__ sigf,
                        float* __restrict__ z_m, int* __restrict__ order,
                        float* __restrict__ wgt) {
  __shared__ float szc[128], szf[128], szm[256], sl[256];
  __shared__ int sord[256];
  int r = blockIdx.x, t = threadIdx.x;  // 256 threads
  if (t < 128) szc[t] = z_c[r * NSTEP + t];
  else szf[t - 128] = z_f[r * NSTEP + t - 128];
  __syncthreads();
  int pos; float myz;
  if (t < 128) {  // coarse i: pos = i + #{zf < zc[i]}   (ties: coarse first)
    myz = szc[t];
    int lo = 0, hi = 128;
    while (lo < hi) { int m = (lo + hi) >> 1; if (szf[m] < myz) lo = m + 1; else hi = m; }
    pos = t + lo;
  } else {        // fine j: pos = j + #{zc <= zf[j]}
    int j = t - 128; myz = szf[j];
    int lo = 0, hi = 128;
    while (lo < hi) { int m = (lo + hi) >> 1; if (szc[m] <= myz) lo = m + 1; else hi = m; }
    pos = j + lo;
  }
  szm[pos] = myz; sord[pos] = t;
  __syncthreads();
  z_m[r * TSAMP + t] = szm[t];
  order[r * TSAMP + t] = sord[t];
  int src = sord[t];
  float sg = (src < 128) ? sigc[r * NSTEP + src] : sigf[r * NSTEP + (src - 128)];
  float zt = szm[t];
  float aug = (t < 255) ? (szm[t + 1] - zt) : (szm[255] - szm[254]);
  float alpha = 1.0f - expf(-aug * sg);
  sl[t] = logf(1.0f - alpha + 1e-15f);
  __syncthreads();
  for (int off = 1; off < 256; off <<= 1) {
    float y = (t >= off) ? sl[t - off] : 0.0f;
    __syncthreads();
    sl[t] += y;
    __syncthreads();
  }
  float excl = (t > 0) ? sl[t - 1] : 0.0f;
  wgt[r * TSAMP + t] = alpha * expf(excl);
}

// ---------------------------------------------------------------- color MLP
__global__ __launch_bounds__(256, 2)
void k_color(const float* __restrict__ rays_d, const int* __restrict__ order,
             const float* __restrict__ wgt,
             const unsigned short* __restrict__ goutc, const unsigned short* __restrict__ goutf,
             const unsigned short* __restrict__ Wp1, const float* __restrict__ cb1,
             const unsigned short* __restrict__ Wp2, const float* __restrict__ cb2,
             const unsigned short* __restrict__ Wp3, const float* __restrict__ cb3,
             float* __restrict__ rgb4) {
  __shared__ unsigned short buf[64 * 256];
  __shared__ unsigned short xb[64 * 32];
  __shared__ unsigned short sW3[4096];
  __shared__ __align__(16) float sb1[256];
  __shared__ __align__(16) float sb2[256];
  const int t = threadIdx.x;
  const int lane = t & 63, wid = t >> 6, quad = lane >> 4, col = lane & 15;
  const int p_ = t >> 2, g_ = t & 3;

  sb1[t] = cb1[t];
  sb2[t] = cb2[t];
  { const u16x8* s = (const u16x8*)Wp3; u16x8* d = (u16x8*)sW3;
    d[t] = s[t]; d[t + 256] = s[t + 256]; }

  bf16x8 w1r[4], w2r[8][4];
#pragma unroll
  for (int ntl = 0; ntl < 4; ++ntl)
    w1r[ntl] = *reinterpret_cast<const bf16x8*>(Wp1 + ((wid * 4 + ntl) * 64 + lane) * 8);
#pragma unroll
  for (int kt = 0; kt < 8; ++kt)
#pragma unroll
    for (int ntl = 0; ntl < 4; ++ntl)
      w2r[kt][ntl] = *reinterpret_cast<const bf16x8*>(Wp2 + ((kt * 16 + wid * 4 + ntl) * 64 + lane) * 8);

  // ---- prologue gather (tile 0): order -> gout chain, dir, wgt
  u16x8 gx = {0, 0, 0, 0, 0, 0, 0, 0};
  float wgtv = 0.0f;
  {
    int P = blockIdx.x * CTPW * 64 + p_;
    int r = P >> 8;
    if (g_ < 2) {
      int src = order[P];
      const unsigned short* gs = (src < 128)
          ? (goutc + (size_t)(r * NSTEP + src) * 16)
          : (goutf + (size_t)(r * NSTEP + (src - 128)) * 16);
      gx = *reinterpret_cast<const u16x8*>(gs + g_ * 8);
    } else if (g_ == 2) {
      gx[0] = f2bf(rays_d[r * 3 + 0]);
      gx[1] = f2bf(rays_d[r * 3 + 1]);
      gx[2] = f2bf(rays_d[r * 3 + 2]);
    } else {
      wgtv = wgt[P];
    }
  }

#pragma unroll 1
  for (int tt = 0; tt < CTPW; ++tt) {
    const int P0 = (blockIdx.x * CTPW + tt) * 64;
    const int haveNext = (tt + 1 < CTPW);
    int go = __syncthreads_or((g_ == 3) && (wgtv > 1e-4f));
    int ordn = 0; float wgtn = 0.0f;
    u16x8 gxn = {0, 0, 0, 0, 0, 0, 0, 0};
    if (go) {
      *reinterpret_cast<u16x8*>(&xb[p_ * 32 + ((g_ ^ (p_ & 3)) * 8)]) = gx;
      __syncthreads();  // xb ready; prev tile's L3 buf-reads retired
      mlp_l1(xb, buf, w1r, sb1, wid, quad, col);
      __syncthreads();  // B2: h1 complete
    }
    if (haveNext) {  // stage 1 of next-tile gather (independent loads)
      int Pn = P0 + 64 + p_;
      int rn = Pn >> 8;
      if (g_ < 2) ordn = order[Pn];
      else if (g_ == 2) {
        gxn[0] = f2bf(rays_d[rn * 3 + 0]);
        gxn[1] = f2bf(rays_d[rn * 3 + 1]);
        gxn[2] = f2bf(rays_d[rn * 3 + 2]);
      } else wgtn = wgt[Pn];
    }
    f32x4 acc[8];
    if (go) {
      l2_half_compute(buf, w2r, acc, 0, quad, col);
      __syncthreads();  // half0 reads done before overwrite
      l2_half_write(buf, acc, sb2, 0, wid, quad, col);
    }
    if (haveNext && g_ < 2) {  // stage 2: dependent gout gather (ordn arrived)
      int Pn = P0 + 64 + p_;
      int rn = Pn >> 8;
      const unsigned short* gs = (ordn < 128)
          ? (goutc + (size_t)(rn * NSTEP + ordn) * 16)
          : (goutf + (size_t)(rn * NSTEP + (ordn - 128)) * 16);
      gxn = *reinterpret_cast<const u16x8*>(gs + g_ * 8);
    }
    if (go) {
      l2_half_compute(buf, w2r, acc, 1, quad, col);
      __syncthreads();  // half1 reads done
      l2_half_write(buf, acc, sb2, 1, wid, quad, col);
      __syncthreads();  // h2 complete
      { // L3: 256 -> 3 (padded 16), sigmoid
        const int p = wid * 16 + col;
        f32x4 a3 = {0.f, 0.f, 0.f, 0.f};
#pragma unroll
        for (int kt = 0; kt < 8; ++kt) {
          bf16x8 w = *reinterpret_cast<const bf16x8*>(&sW3[(kt * 64 + lane) * 8]);
          bf16x8 x = *reinterpret_cast<const bf16x8*>(&buf[p * 256 + (((kt * 4 + quad) ^ (p & 31)) * 8)]);
          a3 = __builtin_amdgcn_mfma_f32_16x16x32_bf16(w, x, a3, 0, 0, 0);
        }
        if (quad == 0) {
          f32x4 v;
#pragma unroll
          for (int rr = 0; rr < 3; ++rr) {
            float s = a3[rr] + cb3[rr];
            v[rr] = 1.0f / (1.0f + expf(-s));
          }
          v[3] = 0.0f;
          *reinterpret_cast<f32x4*>(rgb4 + (size_t)(P0 + p) * 4) = v;
        }
      }
    }
    gx = gxn; wgtv = wgtn;
  }
}

// ------------------------------------------------------- final per-ray outputs
__device__ __forceinline__ float block_reduce(float v, float* s, int t) {
  s[t] = v;
  __syncthreads();
  for (int off = 128; off > 0; off >>= 1) {
    if (t < off) s[t] += s[t + off];
    __syncthreads();
  }
  float r = s[0];
  __syncthreads();
  return r;
}

__global__ void k_final(const float* __restrict__ z_m, const float* __restrict__ wgt,
                        const float* __restrict__ rgb4, float* __restrict__ out) {
  __shared__ float sz[256], sw[256], smid[256], sred[256];
  int r = blockIdx.x, t = threadIdx.x;  // 256 threads
  float zt = z_m[r * TSAMP + t];
  float wt = wgt[r * TSAMP + t];
  sz[t] = zt; sw[t] = wt;
  __syncthreads();
  float znext = (t < 255) ? sz[t + 1] : (1.0f / 128.0f);  // sample_dist
  smid[t] = 0.5f * zt + 0.5f * znext;
  float cr = 0.f, cg = 0.f, cb = 0.f;
  if (wt > 1e-4f) {
    f32x4 c = *reinterpret_cast<const f32x4*>(rgb4 + (size_t)(r * TSAMP + t) * 4);
    cr = c[0]; cg = c[1]; cb = c[2];
  }
  __syncthreads();
  float mt = smid[t];
  float acc = 0.f;
  for (int j = 0; j < 256; ++j) acc += fabsf(mt - smid[j]) * sw[j];
  acc *= wt;
  float wsum = block_reduce(wt, sred, t);
  float depth = block_reduce(wt * zt, sred, t);
  float ir = block_reduce(wt * cr, sred, t);
  float ig = block_reduce(wt * cg, sred, t);
  float ib = block_reduce(wt * cb, sred, t);
  float S = block_reduce(acc, sred, t);
  if (t == 0) {
    const float bgc = 206.0f / 255.0f;
    float loss = S / (depth + 1e-6f);
    if (loss < 1e-3f) loss = 0.0f;
    out[r * 5 + 0] = ir + (1.0f - wsum) * bgc;
    out[r * 5 + 1] = ig + (1.0f - wsum) * bgc;
    out[r * 5 + 2] = ib + (1.0f - wsum) * bgc;
    out[r * 5 + 3] = depth;
    out[r * 5 + 4] = loss;
  }
}

// ---------------------------------------------------------------- launch
extern "C" void kernel_launch(void* const* d_in, const int* in_sizes, int n_in,
                              void* d_out, int out_size, void* d_ws, size_t ws_size,
                              hipStream_t stream) {
  const float* rays_o = (const float*)d_in[0];
  const float* rays_d = (const float*)d_in[1];
  const float* dW1 = (const float*)d_in[2];
  const float* db1 = (const float*)d_in[3];
  const float* dW2 = (const float*)d_in[4];
  const float* db2 = (const float*)d_in[5];
  const float* dW3 = (const float*)d_in[6];
  const float* db3 = (const float*)d_in[7];
  const float* cW1 = (const float*)d_in[8];
  const float* cb1 = (const float*)d_in[9];
  const float* cW2 = (const float*)d_in[10];
  const float* cb2 = (const float*)d_in[11];
  const float* cW3 = (const float*)d_in[12];
  const float* cb3 = (const float*)d_in[13];
  // num_steps / upsample_steps fixed at 128/128 (compile-time).

  char* ws = (char*)d_ws;
  size_t off = 0;
  auto alloc = [&](size_t bytes) -> void* {
    void* p = ws + off;
    off += (bytes + 255) & ~(size_t)255;
    return p;
  };
  unsigned short* Wp_d1 = (unsigned short*)alloc(8192 * 2);
  unsigned short* Wp_d2 = (unsigned short*)alloc(65536 * 2);
  unsigned short* Wp_d3 = (unsigned short*)alloc(4096 * 2);
  unsigned short* Wp_c1 = (unsigned short*)alloc(8192 * 2);
  unsigned short* Wp_c2 = (unsigned short*)alloc(65536 * 2);
  unsigned short* Wp_c3 = (unsigned short*)alloc(4096 * 2);
  float* z_c  = (float*)alloc((size_t)NRAYS * NSTEP * 4);
  float* z_f  = (float*)alloc((size_t)NRAYS * NSTEP * 4);
  unsigned short* goutc = (unsigned short*)alloc((size_t)NRAYS * NSTEP * 16 * 2);
  unsigned short* goutf = (unsigned short*)alloc((size_t)NRAYS * NSTEP * 16 * 2);
  float* sigc = (float*)alloc((size_t)NRAYS * NSTEP * 4);
  float* sigf = (float*)alloc((size_t)NRAYS * NSTEP * 4);
  float* z_m  = (float*)alloc((size_t)NRAYS * TSAMP * 4);
  int*   ordr = (int*)alloc((size_t)NRAYS * TSAMP * 4);
  float* wgt  = (float*)alloc((size_t)NRAYS * TSAMP * 4);
  float* rgb4 = (float*)alloc((size_t)NRAYS * TSAMP * 4 * 4);
  (void)ws_size; (void)in_sizes; (void)n_in; (void)out_size;

  k_pack<<<8192 / 256, 256, 0, stream>>>(dW1, Wp_d1, 3, 256, 16, 8192);
  k_pack<<<65536 / 256, 256, 0, stream>>>(dW2, Wp_d2, 256, 256, 16, 65536);
  k_pack_d3<<<4096 / 256, 256, 0, stream>>>(dW3, Wp_d3);
  k_pack_c1<<<8192 / 256, 256, 0, stream>>>(cW1, Wp_c1);
  k_pack<<<65536 / 256, 256, 0, stream>>>(cW2, Wp_c2, 256, 256, 16, 65536);
  k_pack<<<4096 / 256, 256, 0, stream>>>(cW3, Wp_c3, 256, 3, 1, 4096);

  k_raysetup<<<NRAYS, 128, 0, stream>>>(rays_o, rays_d, z_c);
  k_density<<<(NRAYS * NSTEP) / (64 * DTPW), 256, 0, stream>>>(
      rays_o, rays_d, z_c, Wp_d1, db1, Wp_d2, db2, Wp_d3, db3, goutc, sigc);
  k_pdf<<<NRAYS, 128, 0, stream>>>(z_c, sigc, z_f);
  k_density<<<(NRAYS * NSTEP) / (64 * DTPW), 256, 0, stream>>>(
      rays_o, rays_d, z_f, Wp_d1, db1, Wp_d2, db2, Wp_d3, db3, goutf, sigf);
  k_merge<<<NRAYS, 256, 0, stream>>>(z_c, z_f, sigc, sigf, z_m, ordr, wgt);
  k_color<<<(NRAYS * TSAMP) / (64 * CTPW), 256, 0, stream>>>(
      rays_d, ordr, wgt, goutc, goutf, Wp_c1, cb1, Wp_c2, cb2, Wp_c3, cb3, rgb4);
  k_final<<<NRAYS, 256, 0, stream>>>(z_m, wgt, rgb4, (float*)d_out);
}

// Round 7
// 288.995 us; speedup vs baseline: 1.8593x; 1.0689x over previous
//
#include <hip/hip_runtime.h>

// NeRF renderer pipeline for MI355X (gfx950).
// R7: (1) native bf16 converts ((__bf16) cast -> v_cvt_pk_bf16_f32) replacing
// 4-op manual RNE — R6 showed VALUBusy 48% > MfmaUtil 31%, conversion-bound;
// (2) mega-fusion 13 -> 4 launches: k_pack_all | k_density<true> (z inline +
// fused per-2-ray sample_pdf tail, sigma via LDS) | k_density<false> |
// k_mcf (merge+color+final per ray; order/wgt/z/rgb all LDS-resident).

typedef float f32x4 __attribute__((ext_vector_type(4)));
typedef __bf16 bf16x8 __attribute__((ext_vector_type(8)));
typedef __bf16 bf16x4 __attribute__((ext_vector_type(4)));
typedef unsigned short u16x8 __attribute__((ext_vector_type(8)));
typedef unsigned short u16x4 __attribute__((ext_vector_type(4)));

#define NRAYS 2048
#define NSTEP 128
#define TSAMP 256
#define MIN_NEAR 0.05f
#define DTPW 4   // density tiles (64 pts) per workgroup (= 2 rays/WG)

// packed-weight offsets (u16 elements) inside the single Wp buffer
#define OFF_D1 0
#define OFF_D2 8192
#define OFF_D3 73728
#define OFF_C1 77824
#define OFF_C2 86016
#define OFF_C3 151552
#define PACK_TOTAL 155648

__device__ __forceinline__ unsigned short f2bf(float f) {
  __bf16 h = (__bf16)f;             // native v_cvt on gfx950, RTNE
  return __builtin_bit_cast(unsigned short, h);
}
__device__ __forceinline__ u16x4 pack4(float a, float b, float c, float d) {
  bf16x4 h;
  h[0] = (__bf16)a; h[1] = (__bf16)b; h[2] = (__bf16)c; h[3] = (__bf16)d;
  return __builtin_bit_cast(u16x4, h);
}

// per-ray z for step i (identical arithmetic everywhere for consistency)
__device__ __forceinline__ float ray_z(const float* __restrict__ ro,
                                       const float* __restrict__ rd, int r, int i) {
  float ox = ro[r * 3], oy = ro[r * 3 + 1], oz = ro[r * 3 + 2];
  float dx = rd[r * 3], dy = rd[r * 3 + 1], dz = rd[r * 3 + 2];
  float b = ox * dx + oy * dy + oz * dz;
  float c = ox * ox + oy * oy + oz * oz - 1.0f;
  float disc = fmaxf(b * b - c, 0.0f);
  float zmax = fmaxf(-b + sqrtf(disc), MIN_NEAR + 1e-3f);
  float zmin = MIN_NEAR;
  float tt = (float)i / 127.0f;
  float zz = zmin + (zmax - zmin) * tt;
  return fminf(fmaxf(zz, zmin), zmax);
}

// ---------------------------------------------------------------- weight pack
__device__ __forceinline__ void pack_std(const float* __restrict__ W,
                                         unsigned short* __restrict__ dst,
                                         int idx, int K, int Norig, int NT) {
  int per = NT * 512;
  int kt = idx / per, rm = idx % per;
  int nt = rm >> 9, lane = (rm >> 3) & 63, j = rm & 7;
  int k = kt * 32 + ((lane >> 4) << 3) + j;
  int n = nt * 16 + (lane & 15);
  float v = (k < K && n < Norig) ? W[k * Norig + n] : 0.0f;
  dst[idx] = f2bf(v);
}

__global__ void k_pack_all(const float* __restrict__ dW1, const float* __restrict__ dW2,
                           const float* __restrict__ dW3, const float* __restrict__ cW1,
                           const float* __restrict__ cW2, const float* __restrict__ cW3,
                           unsigned short* __restrict__ Wp) {
  int idx = blockIdx.x * 256 + threadIdx.x;
  if (idx < OFF_D2) {                       // density L1: K=3,N=256
    pack_std(dW1, Wp + OFF_D1, idx - OFF_D1, 3, 256, 16);
  } else if (idx < OFF_D3) {                // density L2
    pack_std(dW2, Wp + OFF_D2, idx - OFF_D2, 256, 256, 16);
  } else if (idx < OFF_C1) {                // density L3, permuted [geo15|sigma]
    int j2 = idx - OFF_D3;
    int lane = (j2 >> 3) & 63, jj = j2 & 7, kt = j2 >> 9;
    int k = kt * 32 + ((lane >> 4) << 3) + jj;
    int n = lane & 15;
    Wp[idx] = f2bf(dW3[k * 16 + ((n + 1) & 15)]);
  } else if (idx < OFF_C2) {                // color L1: X=[geo0..14,0,dir,0..]
    int j2 = idx - OFF_C1;
    int nt = j2 >> 9, lane = (j2 >> 3) & 63, jj = j2 & 7;
    int k = ((lane >> 4) << 3) + jj;
    int n = nt * 16 + (lane & 15);
    float v = 0.0f;
    if (k < 15) v = cW1[(3 + k) * 256 + n];
    else if (k >= 16 && k < 19) v = cW1[(k - 16) * 256 + n];
    Wp[idx] = f2bf(v);
  } else if (idx < OFF_C3) {                // color L2
    pack_std(cW2, Wp + OFF_C2, idx - OFF_C2, 256, 256, 16);
  } else if (idx < PACK_TOTAL) {            // color L3
    pack_std(cW3, Wp + OFF_C3, idx - OFF_C3, 256, 3, 1);
  }
}

// ---------------------------------------------------------------- MFMA helpers
// LDS act layout: h[p][n] at u16 offset p*256 + ((n>>3)^(p&31))*8 + (n&7)
// xb layout: X[p][c] at u16 offset p*32 + ((g^(p&3))*8) + (c&7), g=c>>3

__device__ __forceinline__ void mlp_l1(const unsigned short* xb, unsigned short* buf,
                                       const bf16x8 (&w1r)[4], const float* sb1,
                                       int wid, int quad, int col) {
#pragma unroll
  for (int h = 0; h < 2; ++h) {
    f32x4 acc[8];
#pragma unroll
    for (int i = 0; i < 8; ++i) acc[i] = (f32x4){0.f, 0.f, 0.f, 0.f};
    int p0 = (h * 2) * 16 + col, p1 = (h * 2 + 1) * 16 + col;
    bf16x8 x0 = *reinterpret_cast<const bf16x8*>(&xb[p0 * 32 + ((quad ^ (p0 & 3)) * 8)]);
    bf16x8 x1 = *reinterpret_cast<const bf16x8*>(&xb[p1 * 32 + ((quad ^ (p1 & 3)) * 8)]);
#pragma unroll
    for (int ntl = 0; ntl < 4; ++ntl) {
      acc[ntl * 2 + 0] = __builtin_amdgcn_mfma_f32_16x16x32_bf16(w1r[ntl], x0, acc[ntl * 2 + 0], 0, 0, 0);
      acc[ntl * 2 + 1] = __builtin_amdgcn_mfma_f32_16x16x32_bf16(w1r[ntl], x1, acc[ntl * 2 + 1], 0, 0, 0);
    }
#pragma unroll
    for (int ntl = 0; ntl < 4; ++ntl) {
      int n = (wid * 4 + ntl) * 16 + quad * 4;
      f32x4 bv = *reinterpret_cast<const f32x4*>(&sb1[n]);
#pragma unroll
      for (int j = 0; j < 2; ++j) {
        int p = (h * 2 + j) * 16 + col;
        *reinterpret_cast<u16x4*>(&buf[p * 256 + (((n >> 3) ^ (p & 31)) * 8) + (n & 7)]) =
            pack4(fmaxf(acc[ntl * 2 + j][0] + bv[0], 0.0f),
                  fmaxf(acc[ntl * 2 + j][1] + bv[1], 0.0f),
                  fmaxf(acc[ntl * 2 + j][2] + bv[2], 0.0f),
                  fmaxf(acc[ntl * 2 + j][3] + bv[3], 0.0f));
      }
    }
  }
}

__device__ __forceinline__ void l2_half_compute(const unsigned short* buf,
                                                const bf16x8 (&w2r)[8][4],
                                                f32x4 (&acc)[8], int h, int quad, int col) {
#pragma unroll
  for (int i = 0; i < 8; ++i) acc[i] = (f32x4){0.f, 0.f, 0.f, 0.f};
#pragma unroll
  for (int kt = 0; kt < 8; ++kt) {
    int p0 = (h * 2) * 16 + col, p1 = (h * 2 + 1) * 16 + col;
    bf16x8 x0 = *reinterpret_cast<const bf16x8*>(&buf[p0 * 256 + (((kt * 4 + quad) ^ (p0 & 31)) * 8)]);
    bf16x8 x1 = *reinterpret_cast<const bf16x8*>(&buf[p1 * 256 + (((kt * 4 + quad) ^ (p1 & 31)) * 8)]);
#pragma unroll
    for (int ntl = 0; ntl < 4; ++ntl) {
      acc[ntl * 2 + 0] = __builtin_amdgcn_mfma_f32_16x16x32_bf16(w2r[kt][ntl], x0, acc[ntl * 2 + 0], 0, 0, 0);
      acc[ntl * 2 + 1] = __builtin_amdgcn_mfma_f32_16x16x32_bf16(w2r[kt][ntl], x1, acc[ntl * 2 + 1], 0, 0, 0);
    }
  }
}

__device__ __forceinline__ void l2_half_write(unsigned short* buf, const f32x4 (&acc)[8],
                                              const float* sb2, int h, int wid, int quad, int col) {
#pragma unroll
  for (int ntl = 0; ntl < 4; ++ntl) {
    int n = (wid * 4 + ntl) * 16 + quad * 4;
    f32x4 bv = *reinterpret_cast<const f32x4*>(&sb2[n]);
#pragma unroll
    for (int j = 0; j < 2; ++j) {
      int p = (h * 2 + j) * 16 + col;
      *reinterpret_cast<u16x4*>(&buf[p * 256 + (((n >> 3) ^ (p & 31)) * 8) + (n & 7)]) =
          pack4(fmaxf(acc[ntl * 2 + j][0] + bv[0], 0.0f),
                fmaxf(acc[ntl * 2 + j][1] + bv[1], 0.0f),
                fmaxf(acc[ntl * 2 + j][2] + bv[2], 0.0f),
                fmaxf(acc[ntl * 2 + j][3] + bv[3], 0.0f));
    }
  }
}

// ---------------------------------------------------------------- density MLP
// FIRST: z computed inline (coarse linspace) + fused sample_pdf tail -> z_f.
// !FIRST: z read from zin (= z_f).
template <bool FIRST>
__global__ __launch_bounds__(256, 2)
void k_density(const float* __restrict__ ro, const float* __restrict__ rd,
               const float* __restrict__ zin,
               const unsigned short* __restrict__ Wp1, const float* __restrict__ b1,
               const unsigned short* __restrict__ Wp2, const float* __restrict__ b2,
               const unsigned short* __restrict__ Wp3, const float* __restrict__ b3,
               unsigned short* __restrict__ gout, float* __restrict__ sig,
               float* __restrict__ z_f) {
  __shared__ __align__(16) unsigned short buf[64 * 256];
  __shared__ unsigned short xb[64 * 32];
  __shared__ unsigned short sW3[4096];
  __shared__ __align__(16) float sb1[256];
  __shared__ __align__(16) float sb2[256];
  __shared__ float sb3[16];
  __shared__ float ssig[256];
  const int t = threadIdx.x;
  const int lane = t & 63, wid = t >> 6, quad = lane >> 4, col = lane & 15;
  const int p_ = t >> 2, g_ = t & 3;

  sb1[t] = b1[t];
  sb2[t] = b2[t];
  if (t < 16) sb3[t] = b3[(t + 1) & 15];  // permuted to match pack
  { const u16x8* s = (const u16x8*)Wp3; u16x8* d = (u16x8*)sW3;
    d[t] = s[t]; d[t + 256] = s[t + 256]; }

  bf16x8 w1r[4], w2r[8][4];
#pragma unroll
  for (int ntl = 0; ntl < 4; ++ntl)
    w1r[ntl] = *reinterpret_cast<const bf16x8*>(Wp1 + ((wid * 4 + ntl) * 64 + lane) * 8);
#pragma unroll
  for (int kt = 0; kt < 8; ++kt)
#pragma unroll
    for (int ntl = 0; ntl < 4; ++ntl)
      w2r[kt][ntl] = *reinterpret_cast<const bf16x8*>(Wp2 + ((kt * 16 + wid * 4 + ntl) * 64 + lane) * 8);

#pragma unroll 1
  for (int tt = 0; tt < DTPW; ++tt) {
    const int P0 = blockIdx.x * 256 + tt * 64;
    { // build X = [x,y,z,0..]
      u16x8 pk = {0, 0, 0, 0, 0, 0, 0, 0};
      if (g_ == 0) {
        int P = P0 + p_;
        int rr_ = P >> 7, ii = P & 127;
        float zz;
        if constexpr (FIRST) zz = ray_z(ro, rd, rr_, ii);
        else zz = zin[P];
        pk[0] = f2bf(ro[rr_ * 3 + 0] + rd[rr_ * 3 + 0] * zz);
        pk[1] = f2bf(ro[rr_ * 3 + 1] + rd[rr_ * 3 + 1] * zz);
        pk[2] = f2bf(ro[rr_ * 3 + 2] + rd[rr_ * 3 + 2] * zz);
      }
      *reinterpret_cast<u16x8*>(&xb[p_ * 32 + ((g_ ^ (p_ & 3)) * 8)]) = pk;
    }
    __syncthreads();  // xb ready; prev tile's L3 buf-reads retired
    mlp_l1(xb, buf, w1r, sb1, wid, quad, col);
    __syncthreads();  // h1 complete
    f32x4 acc[8];
    l2_half_compute(buf, w2r, acc, 0, quad, col);
    __syncthreads();
    l2_half_write(buf, acc, sb2, 0, wid, quad, col);
    l2_half_compute(buf, w2r, acc, 1, quad, col);
    __syncthreads();
    l2_half_write(buf, acc, sb2, 1, wid, quad, col);
    __syncthreads();  // h2 complete
    { // L3: 256 -> 16 permuted [geo15 | sigma]
      const int p = wid * 16 + col;
      f32x4 a3 = {0.f, 0.f, 0.f, 0.f};
#pragma unroll
      for (int kt = 0; kt < 8; ++kt) {
        bf16x8 w = *reinterpret_cast<const bf16x8*>(&sW3[(kt * 64 + lane) * 8]);
        bf16x8 x = *reinterpret_cast<const bf16x8*>(&buf[p * 256 + (((kt * 4 + quad) ^ (p & 31)) * 8)]);
        a3 = __builtin_amdgcn_mfma_f32_16x16x32_bf16(w, x, a3, 0, 0, 0);
      }
      int n0 = quad * 4;
      float v0 = a3[0] + sb3[n0], v1 = a3[1] + sb3[n0 + 1];
      float v2 = a3[2] + sb3[n0 + 2], v3 = a3[3] + sb3[n0 + 3];
      if (quad == 3) {  // slot 15 = sigma (trunc_exp); gout slot = 0
        float sgm = expf(fminf(fmaxf(v3, -15.f), 15.f));
        sig[P0 + p] = sgm;
        ssig[tt * 64 + p] = sgm;
        v3 = 0.0f;
      }
      *reinterpret_cast<u16x4*>(gout + (size_t)(P0 + p) * 16 + n0) = pack4(v0, v1, v2, v3);
    }
  }

  if constexpr (FIRST) {  // fused sample_pdf for this WG's 2 rays
    __syncthreads();  // L3 buf-reads retired; ssig complete
    float* pf = reinterpret_cast<float*>(buf);  // alias buf (done with it)
    float* psz = pf;          float* psl = pf + 256;
    float* psw = pf + 512;    float* pcdf = pf + 768;
    float* pmid = pf + 1024;
    const int seg = (t >> 7) * 128;
    const int i = t & 127;
    const int rg = blockIdx.x * 2 + (t >> 7);
    float zi = ray_z(ro, rd, rg, i);
    psz[seg + i] = zi;
    float sgv = ssig[t];
    __syncthreads();
    float aug = (i < 127) ? psz[seg + i + 1] - zi : psz[seg + 127] - psz[seg + 126];
    float alpha = 1.0f - expf(-aug * sgv);
    psl[seg + i] = logf(1.0f - alpha + 1e-15f);
    __syncthreads();
    for (int off = 1; off < 128; off <<= 1) {
      float y = (i >= off) ? psl[seg + i - off] : 0.0f;
      __syncthreads();
      psl[seg + i] += y;
      __syncthreads();
    }
    float excl = (i > 0) ? psl[seg + i - 1] : 0.0f;
    float w = alpha * expf(excl);
    psw[seg + i] = w;
    __syncthreads();
    float v = (i < 126) ? psw[seg + i + 1] + 1e-5f : 0.0f;
    psl[seg + i] = v;
    __syncthreads();
    for (int off = 1; off < 128; off <<= 1) {
      float y = (i >= off) ? psl[seg + i - off] : 0.0f;
      __syncthreads();
      psl[seg + i] += y;
      __syncthreads();
    }
    float total = psl[seg + 125];
    if (i <= 126) pcdf[seg + i] = (i == 0) ? 0.0f : psl[seg + i - 1] / total;
    if (i < 127) pmid[seg + i] = 0.5f * (psz[seg + i] + psz[seg + i + 1]);
    __syncthreads();
    const float lo = 0.5f / 128.0f, hi = 1.0f - 0.5f / 128.0f;
    float u = lo + (hi - lo) * ((float)i / 127.0f);
    int loI = 0, hiI = 127;
    while (loI < hiI) {
      int mid = (loI + hiI) >> 1;
      if (pcdf[seg + mid] > u) hiI = mid; else loI = mid + 1;
    }
    int below = loI - 1; if (below < 0) below = 0; if (below > 126) below = 126;
    int above = loI;     if (above > 126) above = 126;
    float c0 = pcdf[seg + below], c1 = pcdf[seg + above];
    float b0v = pmid[seg + below], b1v = pmid[seg + above];
    float dn = c1 - c0; if (dn < 1e-5f) dn = 1.0f;
    float ttt = (u - c0) / dn;
    z_f[rg * NSTEP + i] = b0v + ttt * (b1v - b0v);
  }
}

// --------------------------------------- merge + color MLP + final (per ray)
__device__ __forceinline__ float block_reduce(float v, float* s, int t) {
  s[t] = v;
  __syncthreads();
  for (int off = 128; off > 0; off >>= 1) {
    if (t < off) s[t] += s[t + off];
    __syncthreads();
  }
  float r = s[0];
  __syncthreads();
  return r;
}

__global__ __launch_bounds__(256, 2)
void k_mcf(const float* __restrict__ ro, const float* __restrict__ rd,
           const float* __restrict__ z_f,
           const float* __restrict__ sigc, const float* __restrict__ sigf,
           const unsigned short* __restrict__ goutc, const unsigned short* __restrict__ goutf,
           const unsigned short* __restrict__ Wp1, const float* __restrict__ cb1,
           const unsigned short* __restrict__ Wp2, const float* __restrict__ cb2,
           const unsigned short* __restrict__ Wp3, const float* __restrict__ cb3,
           float* __restrict__ out) {
  __shared__ __align__(16) unsigned short buf[64 * 256];
  __shared__ unsigned short xb[64 * 32];
  __shared__ unsigned short sW3[4096];
  __shared__ __align__(16) float sb1[256];
  __shared__ __align__(16) float sb2[256];
  __shared__ float szm[256], swgt[256], smid[256], sred[256], sl[256];
  __shared__ float szc[128], szf[128];
  __shared__ float srgb[3 * 256];
  __shared__ int sord[256];
  const int t = threadIdx.x;
  const int lane = t & 63, wid = t >> 6, quad = lane >> 4, col = lane & 15;
  const int p_ = t >> 2, g_ = t & 3;
  const int r = blockIdx.x;

  sb1[t] = cb1[t];
  sb2[t] = cb2[t];
  { const u16x8* s = (const u16x8*)Wp3; u16x8* d = (u16x8*)sW3;
    d[t] = s[t]; d[t + 256] = s[t + 256]; }

  bf16x8 w1r[4], w2r[8][4];
#pragma unroll
  for (int ntl = 0; ntl < 4; ++ntl)
    w1r[ntl] = *reinterpret_cast<const bf16x8*>(Wp1 + ((wid * 4 + ntl) * 64 + lane) * 8);
#pragma unroll
  for (int kt = 0; kt < 8; ++kt)
#pragma unroll
    for (int ntl = 0; ntl < 4; ++ntl)
      w2r[kt][ntl] = *reinterpret_cast<const bf16x8*>(Wp2 + ((kt * 16 + wid * 4 + ntl) * 64 + lane) * 8);

  // ---- merge phase (stable sort of coarse+fine z) ----
  if (t < 128) szc[t] = ray_z(ro, rd, r, t);
  else szf[t - 128] = z_f[r * NSTEP + (t - 128)];
  __syncthreads();
  int pos; float myz;
  if (t < 128) {  // coarse i: pos = i + #{zf < zc[i]} (ties: coarse first)
    myz = szc[t];
    int lo = 0, hi = 128;
    while (lo < hi) { int m = (lo + hi) >> 1; if (szf[m] < myz) lo = m + 1; else hi = m; }
    pos = t + lo;
  } else {        // fine j: pos = j + #{zc <= zf[j]}
    int j = t - 128; myz = szf[j];
    int lo = 0, hi = 128;
    while (lo < hi) { int m = (lo + hi) >> 1; if (szc[m] <= myz) lo = m + 1; else hi = m; }
    pos = j + lo;
  }
  szm[pos] = myz; sord[pos] = t;
  __syncthreads();
  int src = sord[t];
  float sg = (src < 128) ? sigc[r * NSTEP + src] : sigf[r * NSTEP + (src - 128)];
  float zt = szm[t];
  float aug = (t < 255) ? szm[t + 1] - zt : szm[255] - szm[254];
  float alpha = 1.0f - expf(-aug * sg);
  sl[t] = logf(1.0f - alpha + 1e-15f);
  __syncthreads();
  for (int off = 1; off < 256; off <<= 1) {
    float y = (t >= off) ? sl[t - off] : 0.0f;
    __syncthreads();
    sl[t] += y;
    __syncthreads();
  }
  float excl = (t > 0) ? sl[t - 1] : 0.0f;
  swgt[t] = alpha * expf(excl);

  // ---- color phase: 4 tiles of 64 samples; gather prefetched one tile ahead
  float dx0 = rd[r * 3], dx1 = rd[r * 3 + 1], dx2 = rd[r * 3 + 2];
  __syncthreads();  // swgt/sord ready
  u16x8 gx = {0, 0, 0, 0, 0, 0, 0, 0};
  float wgtv = 0.0f;
  {
    if (g_ < 2) {
      int s0 = sord[p_];
      const unsigned short* gs = (s0 < 128)
          ? (goutc + (size_t)(r * NSTEP + s0) * 16)
          : (goutf + (size_t)(r * NSTEP + (s0 - 128)) * 16);
      gx = *reinterpret_cast<const u16x8*>(gs + g_ * 8);
    } else if (g_ == 2) {
      gx[0] = f2bf(dx0); gx[1] = f2bf(dx1); gx[2] = f2bf(dx2);
    } else {
      wgtv = swgt[p_];
    }
  }
#pragma unroll 1
  for (int tt = 0; tt < 4; ++tt) {
    const int P0l = tt * 64;
    const int haveNext = (tt < 3);
    int go = __syncthreads_or((g_ == 3) && (wgtv > 1e-4f));
    u16x8 gxn = {0, 0, 0, 0, 0, 0, 0, 0};
    float wgtn = 0.0f; int ordn = 0;
    if (go) {
      *reinterpret_cast<u16x8*>(&xb[p_ * 32 + ((g_ ^ (p_ & 3)) * 8)]) = gx;
      __syncthreads();
      mlp_l1(xb, buf, w1r, sb1, wid, quad, col);
      __syncthreads();
    }
    if (haveNext) {  // stage 1: LDS order/wgt + uniform dir
      int Pn = P0l + 64 + p_;
      if (g_ < 2) ordn = sord[Pn];
      else if (g_ == 2) { gxn[0] = f2bf(dx0); gxn[1] = f2bf(dx1); gxn[2] = f2bf(dx2); }
      else wgtn = swgt[Pn];
    }
    f32x4 acc[8];
    if (go) {
      l2_half_compute(buf, w2r, acc, 0, quad, col);
      __syncthreads();
      l2_half_write(buf, acc, sb2, 0, wid, quad, col);
    }
    if (haveNext && g_ < 2) {  // stage 2: global gout gather
      const unsigned short* gs = (ordn < 128)
          ? (goutc + (size_t)(r * NSTEP + ordn) * 16)
          : (goutf + (size_t)(r * NSTEP + (ordn - 128)) * 16);
      gxn = *reinterpret_cast<const u16x8*>(gs + g_ * 8);
    }
    if (go) {
      l2_half_compute(buf, w2r, acc, 1, quad, col);
      __syncthreads();
      l2_half_write(buf, acc, sb2, 1, wid, quad, col);
      __syncthreads();
      { // L3: 256 -> 3, sigmoid -> srgb (LDS)
        const int p = wid * 16 + col;
        f32x4 a3 = {0.f, 0.f, 0.f, 0.f};
#pragma unroll
        for (int kt = 0; kt < 8; ++kt) {
          bf16x8 w = *reinterpret_cast<const bf16x8*>(&sW3[(kt * 64 + lane) * 8]);
          bf16x8 x = *reinterpret_cast<const bf16x8*>(&buf[p * 256 + (((kt * 4 + quad) ^ (p & 31)) * 8)]);
          a3 = __builtin_amdgcn_mfma_f32_16x16x32_bf16(w, x, a3, 0, 0, 0);
        }
        if (quad == 0) {
          int pi = P0l + p;
          srgb[pi * 3 + 0] = 1.0f / (1.0f + expf(-(a3[0] + cb3[0])));
          srgb[pi * 3 + 1] = 1.0f / (1.0f + expf(-(a3[1] + cb3[1])));
          srgb[pi * 3 + 2] = 1.0f / (1.0f + expf(-(a3[2] + cb3[2])));
        }
      }
    }
    gx = gxn; wgtv = wgtn;
  }

  // ---- final phase: image/depth/distortion-loss
  __syncthreads();  // srgb complete
  float ztf = szm[t], wtf = swgt[t];
  float znext = (t < 255) ? szm[t + 1] : (1.0f / 128.0f);  // sample_dist
  smid[t] = 0.5f * ztf + 0.5f * znext;
  float cr = 0.f, cg = 0.f, cbv = 0.f;
  if (wtf > 1e-4f) {
    cr = srgb[t * 3]; cg = srgb[t * 3 + 1]; cbv = srgb[t * 3 + 2];
  }
  __syncthreads();
  float mt = smid[t];
  float accl = 0.f;
  for (int j = 0; j < 256; ++j) accl += fabsf(mt - smid[j]) * swgt[j];
  accl *= wtf;
  float wsum = block_reduce(wtf, sred, t);
  float depth = block_reduce(wtf * ztf, sred, t);
  float ir = block_reduce(wtf * cr, sred, t);
  float ig = block_reduce(wtf * cg, sred, t);
  float ib = block_reduce(wtf * cbv, sred, t);
  float S = block_reduce(accl, sred, t);
  if (t == 0) {
    const float bgc = 206.0f / 255.0f;
    float loss = S / (depth + 1e-6f);
    if (loss < 1e-3f) loss = 0.0f;
    out[r * 5 + 0] = ir + (1.0f - wsum) * bgc;
    out[r * 5 + 1] = ig + (1.0f - wsum) * bgc;
    out[r * 5 + 2] = ib + (1.0f - wsum) * bgc;
    out[r * 5 + 3] = depth;
    out[r * 5 + 4] = loss;
  }
}

// ---------------------------------------------------------------- launch
extern "C" void kernel_launch(void* const* d_in, const int* in_sizes, int n_in,
                              void* d_out, int out_size, void* d_ws, size_t ws_size,
                              hipStream_t stream) {
  const float* rays_o = (const float*)d_in[0];
  const float* rays_d = (const float*)d_in[1];
  const float* dW1 = (const float*)d_in[2];
  const float* db1 = (const float*)d_in[3];
  const float* dW2 = (const float*)d_in[4];
  const float* db2 = (const float*)d_in[5];
  const float* dW3 = (const float*)d_in[6];
  const float* db3 = (const float*)d_in[7];
  const float* cW1 = (const float*)d_in[8];
  const float* cb1 = (const float*)d_in[9];
  const float* cW2 = (const float*)d_in[10];
  const float* cb2 = (const float*)d_in[11];
  const float* cW3 = (const float*)d_in[12];
  const float* cb3 = (const float*)d_in[13];
  // num_steps / upsample_steps fixed at 128/128 (compile-time).

  char* ws = (char*)d_ws;
  size_t off = 0;
  auto alloc = [&](size_t bytes) -> void* {
    void* p = ws + off;
    off += (bytes + 255) & ~(size_t)255;
    return p;
  };
  unsigned short* Wp = (unsigned short*)alloc((size_t)PACK_TOTAL * 2);
  unsigned short* goutc = (unsigned short*)alloc((size_t)NRAYS * NSTEP * 16 * 2);
  unsigned short* goutf = (unsigned short*)alloc((size_t)NRAYS * NSTEP * 16 * 2);
  float* sigc = (float*)alloc((size_t)NRAYS * NSTEP * 4);
  float* sigf = (float*)alloc((size_t)NRAYS * NSTEP * 4);
  float* z_f  = (float*)alloc((size_t)NRAYS * NSTEP * 4);
  (void)ws_size; (void)in_sizes; (void)n_in; (void)out_size;

  k_pack_all<<<PACK_TOTAL / 256, 256, 0, stream>>>(dW1, dW2, dW3, cW1, cW2, cW3, Wp);

  k_density<true><<<(NRAYS * NSTEP) / 256, 256, 0, stream>>>(
      rays_o, rays_d, nullptr,
      Wp + OFF_D1, db1, Wp + OFF_D2, db2, Wp + OFF_D3, db3, goutc, sigc, z_f);
  k_density<false><<<(NRAYS * NSTEP) / 256, 256, 0, stream>>>(
      rays_o, rays_d, z_f,
      Wp + OFF_D1, db1, Wp + OFF_D2, db2, Wp + OFF_D3, db3, goutf, sigf, nullptr);
  k_mcf<<<NRAYS, 256, 0, stream>>>(
      rays_o, rays_d, z_f, sigc, sigf, goutc, goutf,
      Wp + OFF_C1, cb1, Wp + OFF_C2, cb2, Wp + OFF_C3, cb3, (float*)d_out);
}